// Round 14
// baseline (996.377 us; speedup 1.0000x reference)
//
#include <hip/hip_runtime.h>
#include <hip/hip_bf16.h>
#include <cstdint>
#include <cstddef>

#define B_ROWS 1024
#define N_CAND 50000
#define CTX    96
#define D_IN   128
#define D_MAIN 256
#define D_BLOCK 512
#define N_OUT  10
#define LN_EPS 1e-5f
#define MAXTIE 4096
#define TKCAP  8192
#define NTOT   (N_CAND + B_ROWS)

typedef unsigned short u16;
typedef __attribute__((ext_vector_type(8))) short bf16x8;
typedef __attribute__((ext_vector_type(4))) float f32x4;

__device__ __forceinline__ u16 bf16_bits(float f) {
    __hip_bfloat16 h = __float2bfloat16(f);
    return *reinterpret_cast<u16*>(&h);
}
__device__ __forceinline__ float bits_to_f32(u16 b) {
    unsigned u = ((unsigned)b) << 16;
    return __uint_as_float(u);
}
__device__ __forceinline__ void split_f32(float v, u16& h, u16& l) {
    h = bf16_bits(v);
    l = bf16_bits(v - bits_to_f32(h));
}
__device__ __forceinline__ float join_f32(u16 h, u16 l) {
    return bits_to_f32(h) + bits_to_f32(l);
}
__device__ __forceinline__ unsigned f2u_mono(float f) {
    unsigned u = __float_as_uint(f);
    return u ^ ((u & 0x80000000u) ? 0xFFFFFFFFu : 0x80000000u);
}

__device__ __forceinline__ void load_lds_16B(const void* gp, void* lp) {
    __builtin_amdgcn_global_load_lds((const __attribute__((address_space(1))) void*)gp,
                                     (__attribute__((address_space(3))) void*)lp,
                                     16, 0, 0);
}

// ---------------------------------------------------------------------------
// Split-bf16 MFMA GEMM (NT). 128x128 tile, BK=32, 1024 threads (16 waves),
// per-wave output 32x32 (acc 2x2). 16x16x32 MFMA. R10-proven (occ 50%+).
// acc += AhBh (+AlBh if A_LO) (+AhBl if B_LO).
// NOTE (R5+R7): per-K-step global fragment loads are a confirmed
// anti-pattern. NOTE (R3): hand-counted vmcnt pipelines likewise.
// KEY16: u16 monotone key of (-2*acc+bias) -> Ch (staged LDS store).
// OUT_SPLIT: (Ch,Cl).  OUT_B16: Ch bf16.  OUT_F32: Cf.  MXFAST: m on blockIdx.x
// MXFAST also applies an XCD-grouping block swizzle (B-panel L2 locality).
// Epilogue LDS tile stride padded 128->136 u16 (bank-conflict fix).
// ---------------------------------------------------------------------------
template<bool RELU, bool HAS_BIAS, bool HAS_RES, bool KEY16,
         bool OUT_F32, bool OUT_SPLIT, bool OUT_B16, bool A_LO, bool B_LO, bool MXFAST>
__global__ __launch_bounds__(1024)
void gemm_split_nt(const u16* __restrict__ Ah, const u16* __restrict__ Al,
                   const u16* __restrict__ Bh, const u16* __restrict__ Bl,
                   const float* __restrict__ bias, const float* __restrict__ Rm,
                   float* __restrict__ Cf, u16* __restrict__ Ch, u16* __restrict__ Cl,
                   int M, int N, int K)
{
    constexpr int nArrA = 1 + (A_LO ? 1 : 0);
    constexpr int nArrB = 1 + (B_LO ? 1 : 0);
    constexpr int NARR  = nArrA + nArrB;
    constexpr int N_LOAD = NARR * 4096;         // u16 per buffer
    constexpr bool STAGED = KEY16 || OUT_SPLIT || OUT_B16;
    constexpr int CS_STRIDE = 136;              // padded epilogue stride
    constexpr int CS_SIZE = 128 * CS_STRIDE;
    constexpr int SM_MIN = STAGED ? CS_SIZE : 0;
    constexpr int SM_U16 = (2 * N_LOAD > SM_MIN) ? 2 * N_LOAD : SM_MIN;
    __shared__ __align__(16) u16 smem[SM_U16];

    constexpr int offAsl = A_LO ? 4096 : 0;
    constexpr int offBsh = 4096 * nArrA;
    constexpr int offBsl = offBsh + (B_LO ? 4096 : 0);

    const int tid  = threadIdx.x;
    const int wave = tid >> 6, lane = tid & 63;

    int bm, bn;
    if constexpr (MXFAST) {
        // XCD-grouping swizzle: blocks sharing a B-panel (same n, all m) land
        // on one XCD for L2 reuse of the streamed B panel.
        const unsigned nbm = gridDim.x;
        const unsigned total = nbm * gridDim.y;
        const unsigned h = blockIdx.x + nbm * blockIdx.y;
        unsigned mi = blockIdx.x, ni = blockIdx.y;
        if ((total & 7u) == 0u) {
            const unsigned per = total >> 3;
            const unsigned virt = (h & 7u) * per + (h >> 3);
            mi = virt % nbm;
            ni = virt / nbm;
        }
        bm = (int)mi * 128; bn = (int)ni * 128;
    } else {
        bm = blockIdx.y * 128; bn = blockIdx.x * 128;
    }

    const int wm = (wave >> 2) * 32, wn = (wave & 3) * 32;
    const int l16 = lane & 15, quad = lane >> 4;

    const int srow = lane >> 2;
    const int scol = (lane & 3) * 8;

    // per-wave staging segments: seg s covers 16 rows x 32 cols of array s>>3
    auto segAddr = [&](int s, const u16*& gp, int& lo) {
        const int a = s >> 3, rb = s & 7;
        const bool isA = (a < nArrA);
        int row = (isA ? bm : bn) + rb * 16 + srow;
        const int mx = (isA ? M : N) - 1;
        if (row > mx) row = mx;
        const u16* base;
        if (a == 0)            base = Ah;
        else if (a == 1)       base = (nArrA > 1) ? Al : Bh;
        else if (a == 2)       base = (nArrA > 1) ? Bh : Bl;
        else                   base = Bl;
        gp = base + (size_t)row * K + scol;
        lo = a * 4096 + rb * 512;
    };

    const u16* sg0; int sl0;
    segAddr(wave, sg0, sl0);
    const u16* sg1 = nullptr; int sl1 = 0;
    constexpr bool SEG1_ALL  = (NARR == 4);
    constexpr bool SEG1_HALF = (NARR == 3);
    if constexpr (SEG1_ALL)  segAddr(wave + 16, sg1, sl1);
    if constexpr (SEG1_HALF) { if (wave < 8) segAddr(wave + 16, sg1, sl1); }

    auto stage = [&](int buf, int k0) {
        u16* base = smem + buf * N_LOAD;
        load_lds_16B(sg0 + k0, &base[sl0]);
        if constexpr (SEG1_ALL)
            load_lds_16B(sg1 + k0, &base[sl1]);
        if constexpr (SEG1_HALF) {
            if (wave < 8) load_lds_16B(sg1 + k0, &base[sl1]);
        }
    };

    f32x4 acc[2][2];
    #pragma unroll
    for (int i = 0; i < 2; ++i)
        #pragma unroll
        for (int j = 0; j < 2; ++j)
            acc[i][j] = (f32x4){0.f, 0.f, 0.f, 0.f};

    stage(0, 0);
    int cur = 0;
    for (int k0 = 0; k0 < K; k0 += 32) {
        __syncthreads();   // drains vmcnt(0): buf[cur] ready; prev reads done

        const u16* Ash = smem + cur * N_LOAD;
        const u16* Asl = Ash + offAsl;
        const u16* Bsh = Ash + offBsh;
        const u16* Bsl = Ash + offBsl;

        bf16x8 ah[2], al[2], bh[2], bl[2];
        #pragma unroll
        for (int i = 0; i < 2; ++i) {
            ah[i] = *(const bf16x8*)&Ash[(wm + i * 16 + l16) * 32 + quad * 8];
            if constexpr (A_LO)
                al[i] = *(const bf16x8*)&Asl[(wm + i * 16 + l16) * 32 + quad * 8];
        }
        #pragma unroll
        for (int j = 0; j < 2; ++j) {
            bh[j] = *(const bf16x8*)&Bsh[(wn + j * 16 + l16) * 32 + quad * 8];
            if constexpr (B_LO)
                bl[j] = *(const bf16x8*)&Bsl[(wn + j * 16 + l16) * 32 + quad * 8];
        }

        if (k0 + 32 < K) stage(cur ^ 1, k0 + 32);   // overlaps with MFMA below

        #pragma unroll
        for (int i = 0; i < 2; ++i)
            #pragma unroll
            for (int j = 0; j < 2; ++j) {
                acc[i][j] = __builtin_amdgcn_mfma_f32_16x16x32_bf16(ah[i], bh[j], acc[i][j], 0, 0, 0);
                if constexpr (A_LO)
                    acc[i][j] = __builtin_amdgcn_mfma_f32_16x16x32_bf16(al[i], bh[j], acc[i][j], 0, 0, 0);
                if constexpr (B_LO)
                    acc[i][j] = __builtin_amdgcn_mfma_f32_16x16x32_bf16(ah[i], bl[j], acc[i][j], 0, 0, 0);
            }
        cur ^= 1;
    }

    float bvj[2];
    #pragma unroll
    for (int j = 0; j < 2; ++j) {
        const int n = bn + wn + j * 16 + l16;
        bvj[j] = ((HAS_BIAS || KEY16) && n < N) ? bias[n] : 0.f;
    }
    auto compute = [&](int i, int j, int r) -> float {
        float v = acc[i][j][r];
        if (KEY16) return -2.f * v + bvj[j];
        if (HAS_BIAS) v += bvj[j];
        if (RELU)     v = fmaxf(v, 0.f);
        if (HAS_RES) {
            const int n = bn + wn + j * 16 + l16;
            const int m = bm + wm + i * 16 + quad * 4 + r;
            v += Rm[(size_t)m * N + n];
        }
        return v;
    };

    if constexpr (OUT_F32) {
        #pragma unroll
        for (int j = 0; j < 2; ++j) {
            const int n = bn + wn + j * 16 + l16;
            if (n >= N) continue;
            #pragma unroll
            for (int i = 0; i < 2; ++i)
                #pragma unroll
                for (int r = 0; r < 4; ++r) {
                    const int m = bm + wm + i * 16 + quad * 4 + r;
                    if (m >= M) continue;
                    Cf[(size_t)m * N + n] = compute(i, j, r);
                }
        }
    }

    if constexpr (STAGED) {
        u16* Cs = smem;
        const int phases = OUT_SPLIT ? 2 : 1;
        for (int ph = 0; ph < phases; ++ph) {
            __syncthreads();
            #pragma unroll
            for (int j = 0; j < 2; ++j) {
                const int nl = wn + j * 16 + l16;
                if (bn + nl >= N) continue;
                #pragma unroll
                for (int i = 0; i < 2; ++i)
                    #pragma unroll
                    for (int r = 0; r < 4; ++r) {
                        const int ml = wm + i * 16 + quad * 4 + r;
                        if (bm + ml >= M) continue;
                        const float v = compute(i, j, r);
                        u16 out;
                        if (KEY16)        out = (u16)(f2u_mono(v) >> 16);
                        else if (OUT_B16) out = bf16_bits(v);
                        else { u16 h, l; split_f32(v, h, l); out = ph ? l : h; }
                        Cs[ml * CS_STRIDE + nl] = out;
                    }
            }
            __syncthreads();
            u16* dstB = (OUT_SPLIT && ph) ? Cl : Ch;
            const int row = tid >> 3, seg = (tid & 7) * 16;
            const int m = bm + row;
            if (m < M) {
                const int ncols = N - bn;
                u16* dst = dstB + (size_t)m * N + bn + seg;
                const u16* srcp = &Cs[row * CS_STRIDE + seg];
                if (ncols >= 128) {
                    #pragma unroll
                    for (int c = 0; c < 2; ++c)
                        *reinterpret_cast<uint4*>(dst + c * 8) =
                            *reinterpret_cast<const uint4*>(srcp + c * 8);
                } else {
                    for (int e = 0; e < 16; ++e)
                        if (seg + e < ncols) dst[e] = srcp[e];
                }
            }
        }
    }
}

// ---------------------------------------------------------------------------
// 64x64-tile split GEMM variant (R14) for SMALL-M dispatches (post chain,
// M=1024): the 128-tile grid gives only 16-32 blocks on 256 CUs (~90% idle).
// 256 threads (4 waves), per-wave 32x32 (acc 2x2), BK=32, same proven
// 2-phase double-buffered staging + staged split epilogue. 4x the blocks.
// Per-element MFMA K-order identical to the 128 variant -> bit-identical.
// ---------------------------------------------------------------------------
template<bool RELU, bool HAS_BIAS, bool HAS_RES,
         bool OUT_F32, bool OUT_SPLIT, bool A_LO, bool B_LO>
__global__ __launch_bounds__(256)
void gemm_split_nt64(const u16* __restrict__ Ah, const u16* __restrict__ Al,
                     const u16* __restrict__ Bh, const u16* __restrict__ Bl,
                     const float* __restrict__ bias, const float* __restrict__ Rm,
                     float* __restrict__ Cf, u16* __restrict__ Ch, u16* __restrict__ Cl,
                     int M, int N, int K)
{
    constexpr int nArrA = 1 + (A_LO ? 1 : 0);
    constexpr int nArrB = 1 + (B_LO ? 1 : 0);
    constexpr int NARR  = nArrA + nArrB;
    constexpr int N_LOAD = NARR * 2048;         // u16 per buffer (64x32/arr)
    constexpr int CS_STRIDE = 72;               // 64 + 8 pad
    constexpr int CS_SIZE = 64 * CS_STRIDE;
    constexpr int SM_MIN = OUT_SPLIT ? CS_SIZE : 0;
    constexpr int SM_U16 = (2 * N_LOAD > SM_MIN) ? 2 * N_LOAD : SM_MIN;
    __shared__ __align__(16) u16 smem[SM_U16];

    constexpr int offAsl = A_LO ? 2048 : 0;
    constexpr int offBsh = 2048 * nArrA;
    constexpr int offBsl = offBsh + (B_LO ? 2048 : 0);

    const int tid  = threadIdx.x;
    const int wave = tid >> 6, lane = tid & 63;

    const int bm = blockIdx.y * 64;
    const int bn = blockIdx.x * 64;

    const int wm = (wave >> 1) * 32, wn = (wave & 1) * 32;
    const int l16 = lane & 15, quad = lane >> 4;

    const int srow = lane >> 2;
    const int scol = (lane & 3) * 8;

    // staging: NARR*4 segments of 16 rows x 32 cols; wave w takes segs
    // {w, w+4, w+8, w+12} (up to NARR of them).
    const u16* sg[4] = {nullptr, nullptr, nullptr, nullptr};
    int sl[4] = {0, 0, 0, 0};
    #pragma unroll
    for (int k = 0; k < NARR; ++k) {
        const int s = wave + 4 * k;           // < NARR*4 guaranteed
        const int a = s >> 2, rb = s & 3;
        const bool isA = (a < nArrA);
        int row = (isA ? bm : bn) + rb * 16 + srow;
        const int mx = (isA ? M : N) - 1;
        if (row > mx) row = mx;
        const u16* base;
        if (a == 0)            base = Ah;
        else if (a == 1)       base = (nArrA > 1) ? Al : Bh;
        else if (a == 2)       base = (nArrA > 1) ? Bh : Bl;
        else                   base = Bl;
        sg[k] = base + (size_t)row * K + scol;
        sl[k] = a * 2048 + rb * 512;
    }

    auto stage = [&](int buf, int k0) {
        u16* base = smem + buf * N_LOAD;
        #pragma unroll
        for (int k = 0; k < NARR; ++k)
            load_lds_16B(sg[k] + k0, &base[sl[k]]);
    };

    f32x4 acc[2][2];
    #pragma unroll
    for (int i = 0; i < 2; ++i)
        #pragma unroll
        for (int j = 0; j < 2; ++j)
            acc[i][j] = (f32x4){0.f, 0.f, 0.f, 0.f};

    stage(0, 0);
    int cur = 0;
    for (int k0 = 0; k0 < K; k0 += 32) {
        __syncthreads();   // drains vmcnt(0): buf[cur] ready; prev reads done

        const u16* Ash = smem + cur * N_LOAD;
        const u16* Asl = Ash + offAsl;
        const u16* Bsh = Ash + offBsh;
        const u16* Bsl = Ash + offBsl;

        bf16x8 ah[2], al[2], bh[2], bl[2];
        #pragma unroll
        for (int i = 0; i < 2; ++i) {
            ah[i] = *(const bf16x8*)&Ash[(wm + i * 16 + l16) * 32 + quad * 8];
            if constexpr (A_LO)
                al[i] = *(const bf16x8*)&Asl[(wm + i * 16 + l16) * 32 + quad * 8];
        }
        #pragma unroll
        for (int j = 0; j < 2; ++j) {
            bh[j] = *(const bf16x8*)&Bsh[(wn + j * 16 + l16) * 32 + quad * 8];
            if constexpr (B_LO)
                bl[j] = *(const bf16x8*)&Bsl[(wn + j * 16 + l16) * 32 + quad * 8];
        }

        if (k0 + 32 < K) stage(cur ^ 1, k0 + 32);   // overlaps with MFMA below

        #pragma unroll
        for (int i = 0; i < 2; ++i)
            #pragma unroll
            for (int j = 0; j < 2; ++j) {
                acc[i][j] = __builtin_amdgcn_mfma_f32_16x16x32_bf16(ah[i], bh[j], acc[i][j], 0, 0, 0);
                if constexpr (A_LO)
                    acc[i][j] = __builtin_amdgcn_mfma_f32_16x16x32_bf16(al[i], bh[j], acc[i][j], 0, 0, 0);
                if constexpr (B_LO)
                    acc[i][j] = __builtin_amdgcn_mfma_f32_16x16x32_bf16(ah[i], bl[j], acc[i][j], 0, 0, 0);
            }
        cur ^= 1;
    }

    float bvj[2];
    #pragma unroll
    for (int j = 0; j < 2; ++j) {
        const int n = bn + wn + j * 16 + l16;
        bvj[j] = (HAS_BIAS && n < N) ? bias[n] : 0.f;
    }
    auto compute = [&](int i, int j, int r) -> float {
        float v = acc[i][j][r];
        if (HAS_BIAS) v += bvj[j];
        if (RELU)     v = fmaxf(v, 0.f);
        if (HAS_RES) {
            const int n = bn + wn + j * 16 + l16;
            const int m = bm + wm + i * 16 + quad * 4 + r;
            v += Rm[(size_t)m * N + n];
        }
        return v;
    };

    if constexpr (OUT_F32) {
        #pragma unroll
        for (int j = 0; j < 2; ++j) {
            const int n = bn + wn + j * 16 + l16;
            if (n >= N) continue;
            #pragma unroll
            for (int i = 0; i < 2; ++i)
                #pragma unroll
                for (int r = 0; r < 4; ++r) {
                    const int m = bm + wm + i * 16 + quad * 4 + r;
                    if (m >= M) continue;
                    Cf[(size_t)m * N + n] = compute(i, j, r);
                }
        }
    }

    if constexpr (OUT_SPLIT) {
        u16* Cs = smem;
        for (int ph = 0; ph < 2; ++ph) {
            __syncthreads();
            #pragma unroll
            for (int j = 0; j < 2; ++j) {
                const int nl = wn + j * 16 + l16;
                if (bn + nl >= N) continue;
                #pragma unroll
                for (int i = 0; i < 2; ++i)
                    #pragma unroll
                    for (int r = 0; r < 4; ++r) {
                        const int ml = wm + i * 16 + quad * 4 + r;
                        if (bm + ml >= M) continue;
                        const float v = compute(i, j, r);
                        u16 h, l; split_f32(v, h, l);
                        Cs[ml * CS_STRIDE + nl] = ph ? l : h;
                    }
            }
            __syncthreads();
            u16* dstB = ph ? Cl : Ch;
            const int row = tid >> 2, seg = (tid & 3) * 16;
            const int m = bm + row;
            if (m < M) {
                const int ncols = N - bn;
                u16* dst = dstB + (size_t)m * N + bn + seg;
                const u16* srcp = &Cs[row * CS_STRIDE + seg];
                if (ncols >= 64) {
                    #pragma unroll
                    for (int c = 0; c < 2; ++c)
                        *reinterpret_cast<uint4*>(dst + c * 8) =
                            *reinterpret_cast<const uint4*>(srcp + c * 8);
                } else {
                    for (int e = 0; e < 16; ++e)
                        if (seg + e < ncols) dst[e] = srcp[e];
                }
            }
        }
    }
}

// ---------------------------------------------------------------------------
// Small-N fp32 GEMM (head, N=10)
// ---------------------------------------------------------------------------
__global__ __launch_bounds__(256)
void gemm_head(const float* __restrict__ A, const float* __restrict__ Bm,
               const float* __restrict__ bias, float* __restrict__ C,
               int M, int N, int K)
{
    __shared__ float As[16][64];
    __shared__ float Bs[16][64];
    const int tid = threadIdx.x;
    const int bm = blockIdx.y * 64;

    const int a_m = tid >> 2;
    const int a_k = (tid & 3) << 2;
    const int b_k = tid >> 4;
    const int b_n = (tid & 15) << 2;
    const int my = (tid >> 4) << 2;
    const int nx = (tid & 15) << 2;

    float acc[4][4] = {};

    for (int k0 = 0; k0 < K; k0 += 16) {
        float4 av = make_float4(0.f,0.f,0.f,0.f);
        const int gm = bm + a_m;
        if (gm < M) av = *(const float4*)(A + (size_t)gm * K + k0 + a_k);
        As[a_k+0][a_m]=av.x; As[a_k+1][a_m]=av.y; As[a_k+2][a_m]=av.z; As[a_k+3][a_m]=av.w;

        float4 bv = make_float4(0.f,0.f,0.f,0.f);
        const float* bp = Bm + (size_t)(k0 + b_k) * N + b_n;
        if (b_n + 0 < N) bv.x = bp[0];
        if (b_n + 1 < N) bv.y = bp[1];
        if (b_n + 2 < N) bv.z = bp[2];
        if (b_n + 3 < N) bv.w = bp[3];
        *(float4*)&Bs[b_k][b_n] = bv;

        __syncthreads();
        #pragma unroll
        for (int k = 0; k < 16; ++k) {
            const float4 a4 = *(const float4*)&As[k][my];
            const float4 b4 = *(const float4*)&Bs[k][nx];
            const float a[4] = {a4.x,a4.y,a4.z,a4.w};
            const float b[4] = {b4.x,b4.y,b4.z,b4.w};
            #pragma unroll
            for (int i = 0; i < 4; ++i)
                #pragma unroll
                for (int j = 0; j < 4; ++j)
                    acc[i][j] = fmaf(a[i], b[j], acc[i][j]);
        }
        __syncthreads();
    }

    #pragma unroll
    for (int i = 0; i < 4; ++i) {
        const int m = bm + my + i;
        if (m >= M) continue;
        #pragma unroll
        for (int j = 0; j < 4; ++j) {
            const int n = nx + j;
            if (n >= N) continue;
            C[(size_t)m * N + n] = acc[i][j] + bias[n];
        }
    }
}

// ---------------------------------------------------------------------------
// LayerNorm over 256 cols; fp32 input; OUT_SPLIT -> (Yh,Yl) else Yf f32.
// ---------------------------------------------------------------------------
template<bool RELU, bool OUT_SPLIT>
__global__ __launch_bounds__(256)
void ln_kernel(const float* __restrict__ X, const float* __restrict__ g,
               const float* __restrict__ b, float* __restrict__ Yf,
               u16* __restrict__ Yh, u16* __restrict__ Yl)
{
    const int row = blockIdx.x, tid = threadIdx.x;
    const float x = X[(size_t)row * D_MAIN + tid];
    __shared__ float red[4];
    const int lane = tid & 63, wid = tid >> 6;

    float s = x;
    #pragma unroll
    for (int off = 32; off; off >>= 1) s += __shfl_down(s, off, 64);
    if (lane == 0) red[wid] = s;
    __syncthreads();
    const float mean = (red[0] + red[1] + red[2] + red[3]) * (1.f / D_MAIN);
    __syncthreads();

    const float xm = x - mean;
    s = xm * xm;
    #pragma unroll
    for (int off = 32; off; off >>= 1) s += __shfl_down(s, off, 64);
    if (lane == 0) red[wid] = s;
    __syncthreads();
    const float var = (red[0] + red[1] + red[2] + red[3]) * (1.f / D_MAIN);

    float y = xm / sqrtf(var + LN_EPS) * g[tid] + b[tid];
    if (RELU) y = fmaxf(y, 0.f);
    if (OUT_SPLIT) {
        u16 h, l; split_f32(y, h, l);
        Yh[(size_t)row * D_MAIN + tid] = h;
        Yl[(size_t)row * D_MAIN + tid] = l;
    } else {
        Yf[(size_t)row * D_MAIN + tid] = y;
    }
}

// ---------------------------------------------------------------------------
// ||cand_k[n]||^2 from split
// ---------------------------------------------------------------------------
__global__ __launch_bounds__(64)
void cn2_kernel(const u16* __restrict__ ckh, const u16* __restrict__ ckl,
                float* __restrict__ out)
{
    const int row = blockIdx.x, lane = threadIdx.x;
    const ushort4 h4 = *(const ushort4*)(ckh + (size_t)row * D_MAIN + lane * 4);
    const ushort4 l4 = *(const ushort4*)(ckl + (size_t)row * D_MAIN + lane * 4);
    const float c0 = join_f32(h4.x, l4.x), c1 = join_f32(h4.y, l4.y);
    const float c2 = join_f32(h4.z, l4.z), c3 = join_f32(h4.w, l4.w);
    float s = c0*c0 + c1*c1 + c2*c2 + c3*c3;
    #pragma unroll
    for (int off = 32; off; off >>= 1) s += __shfl_down(s, off, 64);
    if (lane == 0) out[row] = s;
}

// ---------------------------------------------------------------------------
// conversions
// ---------------------------------------------------------------------------
__global__ __launch_bounds__(256)
void f32_to_split_kernel(const float* __restrict__ src, u16* __restrict__ hi,
                         u16* __restrict__ lo, int n)
{
    int i = blockIdx.x * 256 + threadIdx.x;
    if (i < n) {
        u16 h, l; split_f32(src[i], h, l);
        hi[i] = h; lo[i] = l;
    }
}

struct TrD { const float* s; u16* dh; u16* dl; int R; int C; };
struct TrDs { TrD d[11]; };

__global__ __launch_bounds__(256)
void transpose_all_kernel(TrDs descs)
{
    const TrD D = descs.d[blockIdx.y];
    const int n = D.R * D.C;
    int idx = blockIdx.x * 256 + threadIdx.x;
    if (idx < n) {
        const int r = idx / D.C, c = idx % D.C;
        u16 h, l; split_f32(D.s[idx], h, l);
        D.dh[(size_t)c * D.R + r] = h;
        D.dl[(size_t)c * D.R + r] = l;
    }
}

__global__ __launch_bounds__(256)
void copy_rows_kernel(const float* __restrict__ src, float* __restrict__ dst, int n)
{
    int i = blockIdx.x * 256 + threadIdx.x;
    if (i < n) dst[i] = src[i];
}

// ---------------------------------------------------------------------------
// Top-96 smallest per row on u16 keys — 2-pass + candidate list (R11-proven
// best). Plain per-lane LDS atomics: R12 measured wave-aggregated returning
// atomics NET-NEGATIVE here (ballot/shfl/popc overhead per call exceeds the
// serialization it removes at this predicate density) — do not reintroduce.
// Pass 1: high-byte histogram -> boundary bin hb. Pass 2: low-byte hist
// within hb + collect (lowbyte,idx) candidates + emit hb'<hb directly.
// Pass 3 scans only the candidate list; overflow falls back to full hb-bin
// scan. Selection set identical to the 3-pass version (same T16 partition).
// ---------------------------------------------------------------------------
__global__ __launch_bounds__(1024)
void topk96_u16_kernel(const u16* __restrict__ keys, int* __restrict__ idx_out,
                       int* __restrict__ tiebuf, int* __restrict__ tiecnt,
                       int* __restrict__ lesscnt, unsigned* __restrict__ candbuf)
{
    const int row = blockIdx.x;
    const u16* krow = keys + (size_t)row * N_CAND;
    unsigned* cand = candbuf + (size_t)row * TKCAP;
    const int tid = threadIdx.x;
    const int rep = tid & 63;

    __shared__ unsigned hist[256 * 64];
    __shared__ unsigned hsum[256];
    __shared__ unsigned sh_bin, sh_need;
    __shared__ int cntLess, cntEq, candCnt;

    // ---- pass 1: high-byte histogram ----
    #pragma unroll
    for (int i = 0; i < 16; ++i) hist[tid + i * 1024] = 0;
    __syncthreads();
    for (int i = tid; i < N_CAND / 8; i += 1024) {
        const uint4 v = ((const uint4*)krow)[i];
        const unsigned w[4] = {v.x, v.y, v.z, v.w};
        #pragma unroll
        for (int e = 0; e < 4; ++e) {
            atomicAdd(&hist[(((w[e] >> 8) & 0xFFu)) * 64 + rep], 1u);
            atomicAdd(&hist[((w[e] >> 24)) * 64 + rep], 1u);
        }
    }
    __syncthreads();
    if (tid < 256) {
        unsigned s = 0;
        #pragma unroll
        for (int r = 0; r < 64; ++r) s += hist[tid * 64 + ((r + tid) & 63)];
        hsum[tid] = s;
    }
    __syncthreads();
    int need = CTX;
    if (tid < 64) {
        const unsigned b0 = hsum[tid*4+0], b1 = hsum[tid*4+1],
                       b2 = hsum[tid*4+2], b3 = hsum[tid*4+3];
        const unsigned lsum = b0 + b1 + b2 + b3;
        unsigned pre = lsum;
        #pragma unroll
        for (int off = 1; off < 64; off <<= 1) {
            const unsigned t = __shfl_up(pre, off, 64);
            if (tid >= off) pre += t;
        }
        const unsigned excl = pre - lsum;
        const unsigned nd = (unsigned)need;
        if (excl < nd && excl + lsum >= nd) {
            unsigned bin, rem;
            if      (excl + b0 >= nd)           { bin = tid*4+0; rem = nd - excl; }
            else if (excl + b0 + b1 >= nd)      { bin = tid*4+1; rem = nd - excl - b0; }
            else if (excl + b0 + b1 + b2 >= nd) { bin = tid*4+2; rem = nd - excl - b0 - b1; }
            else                                { bin = tid*4+3; rem = nd - excl - b0 - b1 - b2; }
            sh_bin = bin; sh_need = rem;
        }
    }
    __syncthreads();
    const unsigned hb = sh_bin;
    need = (int)sh_need;
    __syncthreads();

    // ---- pass 2: low-byte hist within hb + emit less + collect candidates ----
    #pragma unroll
    for (int i = 0; i < 16; ++i) hist[tid + i * 1024] = 0;
    if (tid == 0) { cntLess = 0; cntEq = 0; candCnt = 0; }
    __syncthreads();
    for (int i = tid; i < N_CAND / 8; i += 1024) {
        const uint4 v = ((const uint4*)krow)[i];
        const unsigned w[4] = {v.x, v.y, v.z, v.w};
        #pragma unroll
        for (int e = 0; e < 4; ++e) {
            const unsigned k0 = w[e] & 0xFFFFu, k1 = w[e] >> 16;
            const int n0 = i * 8 + e * 2, n1 = n0 + 1;
            const unsigned h0 = k0 >> 8, h1 = k1 >> 8;
            if (h0 == hb) {
                atomicAdd(&hist[(k0 & 255u) * 64 + rep], 1u);
                const int p = atomicAdd(&candCnt, 1);
                if (p < TKCAP) cand[p] = ((k0 & 255u) << 16) | (unsigned)n0;
            } else if (h0 < hb) {
                const int p = atomicAdd(&cntLess, 1);
                idx_out[row * CTX + p] = n0;
            }
            if (h1 == hb) {
                atomicAdd(&hist[(k1 & 255u) * 64 + rep], 1u);
                const int p = atomicAdd(&candCnt, 1);
                if (p < TKCAP) cand[p] = ((k1 & 255u) << 16) | (unsigned)n1;
            } else if (h1 < hb) {
                const int p = atomicAdd(&cntLess, 1);
                idx_out[row * CTX + p] = n1;
            }
        }
    }
    __syncthreads();
    if (tid < 256) {
        unsigned s = 0;
        #pragma unroll
        for (int r = 0; r < 64; ++r) s += hist[tid * 64 + ((r + tid) & 63)];
        hsum[tid] = s;
    }
    __syncthreads();
    if (tid < 64) {
        const unsigned b0 = hsum[tid*4+0], b1 = hsum[tid*4+1],
                       b2 = hsum[tid*4+2], b3 = hsum[tid*4+3];
        const unsigned lsum = b0 + b1 + b2 + b3;
        unsigned pre = lsum;
        #pragma unroll
        for (int off = 1; off < 64; off <<= 1) {
            const unsigned t = __shfl_up(pre, off, 64);
            if (tid >= off) pre += t;
        }
        const unsigned excl = pre - lsum;
        const unsigned nd = (unsigned)need;
        if (excl < nd && excl + lsum >= nd) {
            unsigned bin, rem;
            if      (excl + b0 >= nd)           { bin = tid*4+0; rem = nd - excl; }
            else if (excl + b0 + b1 >= nd)      { bin = tid*4+1; rem = nd - excl - b0; }
            else if (excl + b0 + b1 + b2 >= nd) { bin = tid*4+2; rem = nd - excl - b0 - b1; }
            else                                { bin = tid*4+3; rem = nd - excl - b0 - b1 - b2; }
            sh_bin = bin; sh_need = rem;
        }
    }
    __syncthreads();
    const unsigned lb = sh_bin;
    const int CC = candCnt;
    __syncthreads();

    // ---- pass 3: candidate scan (tiny) or fallback full hb-bin scan ----
    if (CC <= TKCAP) {
        for (int t = tid; t < CC; t += 1024) {
            const unsigned e = cand[t];
            const unsigned l8 = e >> 16;
            const int n = (int)(e & 0xFFFFu);
            if (l8 < lb) {
                const int p = atomicAdd(&cntLess, 1);
                idx_out[row * CTX + p] = n;
            } else if (l8 == lb) {
                const int p = atomicAdd(&cntEq, 1);
                if (p < MAXTIE) tiebuf[(size_t)row * MAXTIE + p] = n;
            }
        }
    } else {
        for (int i = tid; i < N_CAND / 8; i += 1024) {
            const uint4 v = ((const uint4*)krow)[i];
            const unsigned w[4] = {v.x, v.y, v.z, v.w};
            #pragma unroll
            for (int e = 0; e < 4; ++e) {
                const unsigned k0 = w[e] & 0xFFFFu, k1 = w[e] >> 16;
                const int n0 = i * 8 + e * 2, n1 = n0 + 1;
                if ((k0 >> 8) == hb) {
                    const unsigned l8 = k0 & 255u;
                    if (l8 < lb) {
                        const int p = atomicAdd(&cntLess, 1);
                        idx_out[row * CTX + p] = n0;
                    } else if (l8 == lb) {
                        const int p = atomicAdd(&cntEq, 1);
                        if (p < MAXTIE) tiebuf[(size_t)row * MAXTIE + p] = n0;
                    }
                }
                if ((k1 >> 8) == hb) {
                    const unsigned l8 = k1 & 255u;
                    if (l8 < lb) {
                        const int p = atomicAdd(&cntLess, 1);
                        idx_out[row * CTX + p] = n1;
                    } else if (l8 == lb) {
                        const int p = atomicAdd(&cntEq, 1);
                        if (p < MAXTIE) tiebuf[(size_t)row * MAXTIE + p] = n1;
                    }
                }
            }
        }
    }
    __syncthreads();
    if (tid == 0) {
        lesscnt[row] = cntLess;
        tiecnt[row] = (cntEq < MAXTIE) ? cntEq : MAXTIE;
    }
}

// ---------------------------------------------------------------------------
// Fused: exact fp32 tie-break + exact sval for selected 96 + softmax.
// Latency-optimized (R4-proven): MLP-unrolled tie dots, 64-lane parallel bin
// scan, 4-deep pipelined sval gathers, single-wave shfl softmax.
// ---------------------------------------------------------------------------
__global__ __launch_bounds__(256)
void select_kernel(const u16* __restrict__ kh, const u16* __restrict__ kl,
                   const u16* __restrict__ ckh, const u16* __restrict__ ckl,
                   const float* __restrict__ ck2,
                   const int* __restrict__ tiebuf, const int* __restrict__ tiecnt,
                   const int* __restrict__ lesscnt,
                   int* __restrict__ idx_out, float* __restrict__ probs)
{
    const int row = blockIdx.x;
    const int tid = threadIdx.x;
    const int T = tiecnt[row];
    const int less = lesscnt[row];
    const int need = CTX - less;

    __shared__ float kvs[D_MAIN];
    __shared__ int   sel[CTX];
    __shared__ float svals[CTX];
    __shared__ float sv[MAXTIE];
    __shared__ unsigned hist[256];
    __shared__ unsigned sh_bin, sh_need;
    __shared__ int c1, c2;

    if (tid < D_MAIN)
        kvs[tid] = join_f32(kh[(size_t)row * D_MAIN + tid], kl[(size_t)row * D_MAIN + tid]);
    if (tid < CTX && tid < less) sel[tid] = idx_out[row * CTX + tid];
    __syncthreads();

    if (T <= need) {
        for (int t = tid; t < T; t += 256) {
            sel[less + t] = tiebuf[(size_t)row * MAXTIE + t];
            idx_out[row * CTX + less + t] = sel[less + t];
        }
    } else {
        for (int t = tid; t < T; t += 256) {
            const int c = tiebuf[(size_t)row * MAXTIE + t];
            const u16* ch = ckh + (size_t)c * D_MAIN;
            const u16* cl = ckl + (size_t)c * D_MAIN;
            float s = 0.f;
            #pragma unroll 8
            for (int d = 0; d < D_MAIN; d += 4) {
                const ushort4 h4 = *(const ushort4*)(ch + d);
                const ushort4 l4 = *(const ushort4*)(cl + d);
                s += kvs[d+0] * join_f32(h4.x, l4.x) + kvs[d+1] * join_f32(h4.y, l4.y)
                   + kvs[d+2] * join_f32(h4.z, l4.z) + kvs[d+3] * join_f32(h4.w, l4.w);
            }
            sv[t] = ck2[c] - 2.f * s;
        }
        __syncthreads();

        unsigned prefix = 0;
        int plen = 0;
        int nd = need;
        for (int pass = 0; pass < 4; ++pass) {
            const int shift = 24 - 8 * pass;
            hist[tid] = 0;
            __syncthreads();
            for (int t = tid; t < T; t += 256) {
                const unsigned u = f2u_mono(sv[t]);
                if (plen == 0 || (u >> (32 - plen)) == prefix)
                    atomicAdd(&hist[(u >> shift) & 255u], 1u);
            }
            __syncthreads();
            if (tid < 64) {   // parallel 256-bin boundary scan (64-lane prefix)
                const unsigned b0 = hist[tid*4+0], b1 = hist[tid*4+1],
                               b2 = hist[tid*4+2], b3 = hist[tid*4+3];
                const unsigned lsum = b0 + b1 + b2 + b3;
                unsigned pre = lsum;
                #pragma unroll
                for (int off = 1; off < 64; off <<= 1) {
                    const unsigned tt = __shfl_up(pre, off, 64);
                    if (tid >= off) pre += tt;
                }
                const unsigned excl = pre - lsum;
                const unsigned ndu = (unsigned)nd;
                if (excl < ndu && excl + lsum >= ndu) {
                    unsigned bin, rem;
                    if      (excl + b0 >= ndu)           { bin = tid*4+0; rem = ndu - excl; }
                    else if (excl + b0 + b1 >= ndu)      { bin = tid*4+1; rem = ndu - excl - b0; }
                    else if (excl + b0 + b1 + b2 >= ndu) { bin = tid*4+2; rem = ndu - excl - b0 - b1; }
                    else                                 { bin = tid*4+3; rem = ndu - excl - b0 - b1 - b2; }
                    sh_bin = bin; sh_need = rem;
                }
            }
            __syncthreads();
            prefix = (prefix << 8) | sh_bin;
            nd = (int)sh_need;
            plen += 8;
            __syncthreads();
        }
        const unsigned Tf = prefix;
        const int nl2 = need - nd;
        if (tid == 0) { c1 = 0; c2 = 0; }
        __syncthreads();
        for (int t = tid; t < T; t += 256) {
            const unsigned u = f2u_mono(sv[t]);
            if (u < Tf) {
                const int p = atomicAdd(&c1, 1);
                sel[less + p] = tiebuf[(size_t)row * MAXTIE + t];
                idx_out[row * CTX + less + p] = sel[less + p];
            } else if (u == Tf) {
                const int p = atomicAdd(&c2, 1);
                if (p < nd) {
                    sel[less + nl2 + p] = tiebuf[(size_t)row * MAXTIE + t];
                    idx_out[row * CTX + less + nl2 + p] = sel[less + nl2 + p];
                }
            }
        }
    }
    __syncthreads();

    // exact sval for selected 96: 4 rows in flight per wave (MLP)
    const int wv = tid >> 6, lane = tid & 63;
    #pragma unroll
    for (int k = 0; k < 24; k += 4) {
        int ids[4];
        ushort4 h4[4], l4[4];
        #pragma unroll
        for (int u = 0; u < 4; ++u) {
            const int c = wv + 4 * (k + u);
            ids[u] = sel[c];
            h4[u] = *(const ushort4*)(ckh + (size_t)ids[u] * D_MAIN + lane * 4);
            l4[u] = *(const ushort4*)(ckl + (size_t)ids[u] * D_MAIN + lane * 4);
        }
        #pragma unroll
        for (int u = 0; u < 4; ++u) {
            const int c = wv + 4 * (k + u);
            float s = kvs[lane*4+0] * join_f32(h4[u].x, l4[u].x)
                    + kvs[lane*4+1] * join_f32(h4[u].y, l4[u].y)
                    + kvs[lane*4+2] * join_f32(h4[u].z, l4[u].z)
                    + kvs[lane*4+3] * join_f32(h4[u].w, l4[u].w);
            #pragma unroll
            for (int off = 32; off; off >>= 1) s += __shfl_down(s, off, 64);
            if (lane == 0) svals[c] = ck2[ids[u]] - 2.f * s;
        }
    }
    __syncthreads();

    // softmax over 96 in one wave (no barriers)
    if (tid < 64) {
        const float a = -svals[tid];
        const float b = (tid < 32) ? -svals[64 + tid] : -1e30f;
        float m = fmaxf(a, b);
        #pragma unroll
        for (int off = 32; off; off >>= 1) m = fmaxf(m, __shfl_xor(m, off, 64));
        const float ea = __expf(a - m);
        const float eb = (tid < 32) ? __expf(b - m) : 0.f;
        float ssum = ea + eb;
        #pragma unroll
        for (int off = 32; off; off >>= 1) ssum += __shfl_xor(ssum, off, 64);
        const float inv = 1.f / ssum;
        probs[row * CTX + tid] = ea * inv;
        if (tid < 32) probs[row * CTX + 64 + tid] = eb * inv;
    }
}

// ---------------------------------------------------------------------------
// Fused T-MLP collapse via linearity of W1 AND W2:
//   relu((k_b - ck_c)@W1 + b1) = relu(Q[N_CAND+b] + b1 - Q[id_c])
//   u[b]  = sum_c p_c * relu(...)              (512 cols, fp32, kept in LDS)
//   h[b] += sum_c p_c * label_emb[cy[id_c]]  + u[b] @ T_W2   (all fp32)
// ---------------------------------------------------------------------------
__global__ __launch_bounds__(256)
void tmix_kernel(const float* __restrict__ Q, const float* __restrict__ b1,
                 const float* __restrict__ W2, const float* __restrict__ probs,
                 const int* __restrict__ idx, const int* __restrict__ cy,
                 const float* __restrict__ label_emb, float* __restrict__ h)
{
    const int b = blockIdx.x, tid = threadIdx.x;
    __shared__ float pr[CTX];
    __shared__ int   ids[CTX];
    __shared__ int   labs[CTX];
    __shared__ float lemb[N_OUT * D_MAIN];
    __shared__ float uv[D_BLOCK];
    if (tid < CTX) {
        const int id = idx[b * CTX + tid];
        ids[tid]  = id;
        pr[tid]   = probs[b * CTX + tid];
        labs[tid] = cy[id];
    }
    for (int i = tid; i < N_OUT * D_MAIN; i += 256) lemb[i] = label_emb[i];
    __syncthreads();

    const int j0 = tid * 2;
    const float2 pb = *(const float2*)(Q + (size_t)(N_CAND + b) * D_BLOCK + j0);
    const float p0 = pb.x + b1[j0];
    const float p1 = pb.y + b1[j0 + 1];
    float a0 = 0.f, a1 = 0.f, ahd = 0.f;
    #pragma unroll 4
    for (int c = 0; c < CTX; ++c) {
        const float p = pr[c];
        const float2 q = *(const float2*)(Q + (size_t)ids[c] * D_BLOCK + j0);
        a0  = fmaf(p, fmaxf(p0 - q.x, 0.f), a0);
        a1  = fmaf(p, fmaxf(p1 - q.y, 0.f), a1);
        ahd = fmaf(p, lemb[labs[c] * D_MAIN + tid], ahd);
    }
    uv[j0] = a0;
    uv[j0 + 1] = a1;
    __syncthreads();

    // out[tid] = ahd + sum_k uv[k] * W2[k][tid]   (W2 row reads coalesced)
    float o = ahd;
    #pragma unroll 8
    for (int k = 0; k < D_BLOCK; ++k)
        o = fmaf(uv[k], W2[(size_t)k * D_MAIN + tid], o);
    h[(size_t)b * D_MAIN + tid] += o;
}

// ---------------------------------------------------------------------------
// host-side orchestration
// ---------------------------------------------------------------------------
static inline dim3 g128(int M, int N) {
    return dim3((unsigned)((N + 127) / 128), (unsigned)((M + 127) / 128));
}
static inline dim3 g64(int M, int N) {
    return dim3((unsigned)((N + 63) / 64), (unsigned)((M + 63) / 64));
}

struct EncW {
    const u16 *WlinTh, *WlinTl, *e0W1Th, *e0W1Tl, *e0W2Th, *e0W2Tl,
              *e1W1Th, *e1W1Tl, *e1W2Th, *e1W2Tl, *KWTh, *KWTl;
    const float *b_lin, *e0b1, *e0b2, *e1g, *e1b, *e1b1, *e1b2, *mixg, *mixb, *Kb;
};

// encoder: fp32 H stream + split activations, split weights (3 MFMA)
static void encode_rows_split(const u16* Xh, const u16* Xl, int R, const EncW& w,
                              float* H, u16* Hh, u16* Hl, u16* Th, u16* Tl,
                              u16* TNh, u16* TNl, u16* Kh, u16* Kl,
                              hipStream_t stream)
{
    dim3 blk(1024);
    gemm_split_nt<false,true,false,false, true,true,false, true,true,false><<<g128(R, D_MAIN), blk, 0, stream>>>(
        Xh, Xl, w.WlinTh, w.WlinTl, w.b_lin, nullptr, H, Hh, Hl, R, D_MAIN, D_IN);
    gemm_split_nt<true,true,false,false, false,true,false, true,true,false><<<g128(R, D_BLOCK), blk, 0, stream>>>(
        Hh, Hl, w.e0W1Th, w.e0W1Tl, w.e0b1, nullptr, nullptr, Th, Tl, R, D_BLOCK, D_MAIN);
    gemm_split_nt<false,true,true,false, true,false,false, true,true,false><<<g128(R, D_MAIN), blk, 0, stream>>>(
        Th, Tl, w.e0W2Th, w.e0W2Tl, w.e0b2, H, H, nullptr, nullptr, R, D_MAIN, D_BLOCK);
    ln_kernel<false,true><<<R, 256, 0, stream>>>(H, w.e1g, w.e1b, nullptr, TNh, TNl);
    gemm_split_nt<true,true,false,false, false,true,false, true,true,false><<<g128(R, D_BLOCK), blk, 0, stream>>>(
        TNh, TNl, w.e1W1Th, w.e1W1Tl, w.e1b1, nullptr, nullptr, Th, Tl, R, D_BLOCK, D_MAIN);
    gemm_split_nt<false,true,true,false, true,false,false, true,true,false><<<g128(R, D_MAIN), blk, 0, stream>>>(
        Th, Tl, w.e1W2Th, w.e1W2Tl, w.e1b2, H, H, nullptr, nullptr, R, D_MAIN, D_BLOCK);
    ln_kernel<false,true><<<R, 256, 0, stream>>>(H, w.mixg, w.mixb, nullptr, TNh, TNl);
    gemm_split_nt<false,true,false,false, false,true,false, true,true,false><<<g128(R, D_MAIN), blk, 0, stream>>>(
        TNh, TNl, w.KWTh, w.KWTl, w.Kb, nullptr, nullptr, Kh, Kl, R, D_MAIN, D_MAIN);
}

extern "C" void kernel_launch(void* const* d_in, const int* in_sizes, int n_in,
                              void* d_out, int out_size, void* d_ws, size_t ws_size,
                              hipStream_t stream)
{
    const float* x        = (const float*)d_in[0];
    const float* cand_x   = (const float*)d_in[1];
    const int*   cand_y   = (const int*)  d_in[2];
    const float* W_lin    = (const float*)d_in[4];
    const float* b_lin    = (const float*)d_in[5];
    const float* e0W1     = (const float*)d_in[6];
    const float* e0b1     = (const float*)d_in[7];
    const float* e0W2     = (const float*)d_in[8];
    const float* e0b2     = (const float*)d_in[9];
    const float* e1g      = (const float*)d_in[10];
    const float* e1b      = (const float*)d_in[11];
    const float* e1W1     = (const float*)d_in[12];
    const float* e1b1     = (const float*)d_in[13];
    const float* e1W2     = (const float*)d_in[14];
    const float* e1b2     = (const float*)d_in[15];
    const float* mixg     = (const float*)d_in[16];
    const float* mixb     = (const float*)d_in[17];
    const float* K_W      = (const float*)d_in[18];
    const float* K_b      = (const float*)d_in[19];
    const float* label_emb= (const float*)d_in[20];
    const float* T_W1     = (const float*)d_in[21];
    const float* T_b1     = (const float*)d_in[22];
    const float* T_W2     = (const float*)d_in[23];
    const float* p0g      = (const float*)d_in[24];
    const float* p0b      = (const float*)d_in[25];
    const float* p0W1     = (const float*)d_in[26];
    const float* p0b1     = (const float*)d_in[27];
    const float* p0W2     = (const float*)d_in[28];
    const float* p0b2     = (const float*)d_in[29];
    const float* p1g      = (const float*)d_in[30];
    const float* p1b      = (const float*)d_in[31];
    const float* p1W1     = (const float*)d_in[32];
    const float* p1b1     = (const float*)d_in[33];
    const float* p1W2     = (const float*)d_in[34];
    const float* p1b2     = (const float*)d_in[35];
    const float* headg    = (const float*)d_in[36];
    const float* headb    = (const float*)d_in[37];
    const float* head_W   = (const float*)d_in[38];
    const float* head_bias= (const float*)d_in[39];

    char* ws = (char*)d_ws;
    size_t off = 0;
    auto alloc = [&](size_t bytes) -> char* {
        char* p = ws + off;
        off += (bytes + 255) & ~(size_t)255;
        return p;
    };

    u16* in_h   = (u16*)alloc((size_t)NTOT * D_IN * 2);
    u16* in_l   = (u16*)alloc((size_t)NTOT * D_IN * 2);
    u16* allk_h = (u16*)alloc((size_t)NTOT * D_MAIN * 2);
    u16* allk_l = (u16*)alloc((size_t)NTOT * D_MAIN * 2);
    float* ck2  = (float*)alloc((size_t)N_CAND * 4);
    float* h_x  = (float*)alloc((size_t)B_ROWS * D_MAIN * 4);
    float* tn_x = (float*)alloc((size_t)B_ROWS * D_MAIN * 4);
    u16* tnb_h  = (u16*)alloc((size_t)B_ROWS * D_MAIN * 2);
    u16* tnb_l  = (u16*)alloc((size_t)B_ROWS * D_MAIN * 2);
    u16* tb_h   = (u16*)alloc((size_t)B_ROWS * D_BLOCK * 2);
    u16* tb_l   = (u16*)alloc((size_t)B_ROWS * D_BLOCK * 2);
    int*   idx  = (int*)  alloc((size_t)B_ROWS * CTX * 4);
    float* probs= (float*)alloc((size_t)B_ROWS * CTX * 4);
    int* tiecnt = (int*)  alloc((size_t)B_ROWS * 4);
    int* lesscnt= (int*)  alloc((size_t)B_ROWS * 4);

    auto allocW = [&](int R, int C, u16** h, u16** l) {
        *h = (u16*)alloc((size_t)R * C * 2);
        *l = (u16*)alloc((size_t)R * C * 2);
    };
    u16 *WlinTh, *WlinTl, *e0W1Th, *e0W1Tl, *e0W2Th, *e0W2Tl,
        *e1W1Th, *e1W1Tl, *e1W2Th, *e1W2Tl, *KWTh, *KWTl,
        *TW1Th, *TW1Tl,
        *p0W1Th, *p0W1Tl, *p0W2Th, *p0W2Tl, *p1W1Th, *p1W1Tl, *p1W2Th, *p1W2Tl;
    allocW(D_IN,   D_MAIN, &WlinTh, &WlinTl);
    allocW(D_MAIN, D_BLOCK,&e0W1Th, &e0W1Tl);
    allocW(D_BLOCK,D_MAIN, &e0W2Th, &e0W2Tl);
    allocW(D_MAIN, D_BLOCK,&e1W1Th, &e1W1Tl);
    allocW(D_BLOCK,D_MAIN, &e1W2Th, &e1W2Tl);
    allocW(D_MAIN, D_MAIN, &KWTh,   &KWTl);
    allocW(D_MAIN, D_BLOCK,&TW1Th,  &TW1Tl);
    allocW(D_MAIN, D_BLOCK,&p0W1Th, &p0W1Tl);
    allocW(D_BLOCK,D_MAIN, &p0W2Th, &p0W2Tl);
    allocW(D_MAIN, D_BLOCK,&p1W1Th, &p1W1Tl);
    allocW(D_BLOCK,D_MAIN, &p1W2Th, &p1W2Tl);

    // tiebuf last among fixed allocs: Q (NTOT x 512 fp32, ~99.7 MiB) overlays
    // tiebuf (dead after select_kernel) and extends into the pool.
    int* tiebuf = (int*)alloc((size_t)B_ROWS * MAXTIE * 4);

    u16* k_x_h = allk_h + (size_t)N_CAND * D_MAIN;
    u16* k_x_l = allk_l + (size_t)N_CAND * D_MAIN;
    u16* x_in_h = in_h + (size_t)N_CAND * D_IN;
    u16* x_in_l = in_l + (size_t)N_CAND * D_IN;

    const size_t pool_avail = (ws_size > off) ? (ws_size - off) : 0;
    int rc_enc = (int)(pool_avail / 5120);
    if (rc_enc > NTOT) rc_enc = NTOT;
    if (rc_enc < 6250) rc_enc = 6250;
    // per-row: keys (2*N_CAND bytes) + candidate buffer (4*TKCAP bytes)
    int mb_ch = (int)(pool_avail / ((size_t)2 * N_CAND + 4 * TKCAP));
    if (mb_ch > B_ROWS) mb_ch = B_ROWS;
    mb_ch &= ~127;
    if (mb_ch < 128)    mb_ch = 128;

    char* pool = ws + off;
    dim3 blk(256);
    dim3 blkg(1024);

    // 0) conversions
    {
        f32_to_split_kernel<<<(N_CAND*D_IN + 255)/256, blk, 0, stream>>>(cand_x, in_h, in_l, N_CAND*D_IN);
        f32_to_split_kernel<<<(B_ROWS*D_IN + 255)/256, blk, 0, stream>>>(x, x_in_h, x_in_l, B_ROWS*D_IN);
        TrDs tr;
        tr.d[0]  = { W_lin, WlinTh, WlinTl, D_IN,   D_MAIN };
        tr.d[1]  = { e0W1,  e0W1Th, e0W1Tl, D_MAIN, D_BLOCK };
        tr.d[2]  = { e0W2,  e0W2Th, e0W2Tl, D_BLOCK,D_MAIN };
        tr.d[3]  = { e1W1,  e1W1Th, e1W1Tl, D_MAIN, D_BLOCK };
        tr.d[4]  = { e1W2,  e1W2Th, e1W2Tl, D_BLOCK,D_MAIN };
        tr.d[5]  = { K_W,   KWTh,   KWTl,   D_MAIN, D_MAIN };
        tr.d[6]  = { T_W1,  TW1Th,  TW1Tl,  D_MAIN, D_BLOCK };
        tr.d[7]  = { p0W1,  p0W1Th, p0W1Tl, D_MAIN, D_BLOCK };
        tr.d[8]  = { p0W2,  p0W2Th, p0W2Tl, D_BLOCK,D_MAIN };
        tr.d[9]  = { p1W1,  p1W1Th, p1W1Tl, D_MAIN, D_BLOCK };
        tr.d[10] = { p1W2,  p1W2Th, p1W2Tl, D_BLOCK,D_MAIN };
        transpose_all_kernel<<<dim3(512, 11), blk, 0, stream>>>(tr);
    }

    EncW w = { WlinTh, WlinTl, e0W1Th, e0W1Tl, e0W2Th, e0W2Tl,
               e1W1Th, e1W1Tl, e1W2Th, e1W2Tl, KWTh, KWTl,
               b_lin, e0b1, e0b2, e1g, e1b, e1b1, e1b2, mixg, mixb, K_b };

    // 1) combined encode (candidates + x)
    for (int r0 = 0; r0 < NTOT; r0 += rc_enc) {
        const int R = (NTOT - r0 < rc_enc) ? (NTOT - r0) : rc_enc;
        char* p = pool;
        float* Hc = (float*)p;        p += (size_t)rc_enc * D_MAIN * 4;
        u16* Hh  = (u16*)p;           p += (size_t)rc_enc * D_MAIN * 2;
        u16* Hl  = (u16*)p;           p += (size_t)rc_enc * D_MAIN * 2;
        u16* Th  = (u16*)p;           p += (size_t)rc_enc * D_BLOCK * 2;
        u16* Tl  = (u16*)p;           p += (size_t)rc_enc * D_BLOCK * 2;
        u16* TNh = (u16*)p;           p += (size_t)rc_enc * D_MAIN * 2;
        u16* TNl = (u16*)p;
        encode_rows_split(in_h + (size_t)r0 * D_IN, in_l + (size_t)r0 * D_IN,
                          R, w, Hc, Hh, Hl, Th, Tl, TNh, TNl,
                          allk_h + (size_t)r0 * D_MAIN,
                          allk_l + (size_t)r0 * D_MAIN, stream);
        const int lo = (r0 > N_CAND) ? r0 : N_CAND;
        const int hi = (r0 + R < NTOT) ? r0 + R : NTOT;
        if (lo < hi) {
            const int n = (hi - lo) * D_MAIN;
            copy_rows_kernel<<<(n + 255)/256, blk, 0, stream>>>(
                Hc + (size_t)(lo - r0) * D_MAIN, h_x + (size_t)(lo - N_CAND) * D_MAIN, n);
        }
    }

    // 2) candidate norms
    cn2_kernel<<<N_CAND, 64, 0, stream>>>(allk_h, allk_l, ck2);

    // 3+4) distance keys (bf16-hi only) + top-96 select (2-pass + cand list)
    for (int m0 = 0; m0 < B_ROWS; m0 += mb_ch) {
        const int R = (B_ROWS - m0 < mb_ch) ? (B_ROWS - m0) : mb_ch;
        u16* s_keys = (u16*)pool;
        unsigned* candbuf = (unsigned*)(pool + (size_t)mb_ch * N_CAND * 2);
        dim3 grid((unsigned)((R + 127) / 128), (unsigned)((N_CAND + 127) / 128));
        gemm_split_nt<false,false,false,true, false,false,false, false,false,true><<<grid, blkg, 0, stream>>>(
            k_x_h + (size_t)m0 * D_MAIN, nullptr,
            allk_h, nullptr, ck2, nullptr, nullptr, s_keys, nullptr,
            R, N_CAND, D_MAIN);
        topk96_u16_kernel<<<R, 1024, 0, stream>>>(
            s_keys, idx + m0 * CTX, tiebuf + (size_t)m0 * MAXTIE,
            tiecnt + m0, lesscnt + m0, candbuf);
    }

    // 5) fused exact tie-break + sval + softmax
    select_kernel<<<B_ROWS, 256, 0, stream>>>(k_x_h, k_x_l, allk_h, allk_l, ck2,
                                              tiebuf, tiecnt, lesscnt, idx, probs);

    // 6) T-MLP via linearity of W1 and W2:
    //    Q = allk @ T_W1 (all NTOT rows, fp32). tmix collapses
    //    relu(P_b + b1 - Q_c) with probs, folds the label mix AND the
    //    u @ T_W2 product (fp32 W2, coalesced row reads) into h_x.
    float* Qbuf = (float*)tiebuf;   // tiebuf + pool; needs ~99.7 MiB total
    gemm_split_nt<false,false,false,false, true,false,false, true,true,false><<<g128(NTOT, D_BLOCK), blkg, 0, stream>>>(
        allk_h, allk_l, TW1Th, TW1Tl, nullptr, nullptr, Qbuf, nullptr, nullptr,
        NTOT, D_BLOCK, D_MAIN);
    tmix_kernel<<<B_ROWS, 256, 0, stream>>>(Qbuf, T_b1, T_W2, probs, idx,
                                            cand_y, label_emb, h_x);

    // 7) post blocks — M=1024 is tiny for the 128-tile (32 blocks on 256 CUs),
    //    so use the 64x64-tile variant: 4x the blocks, same math/bit-identical.
    ln_kernel<false,true><<<B_ROWS, 256, 0, stream>>>(h_x, p0g, p0b, nullptr, tnb_h, tnb_l);
    gemm_split_nt64<true,true,false, false,true, true,true><<<g64(B_ROWS, D_BLOCK), blk, 0, stream>>>(
        tnb_h, tnb_l, p0W1Th, p0W1Tl, p0b1, nullptr, nullptr, tb_h, tb_l, B_ROWS, D_BLOCK, D_MAIN);
    gemm_split_nt64<false,true,true, true,false, true,true><<<g64(B_ROWS, D_MAIN), blk, 0, stream>>>(
        tb_h, tb_l, p0W2Th, p0W2Tl, p0b2, h_x, h_x, nullptr, nullptr, B_ROWS, D_MAIN, D_BLOCK);
    ln_kernel<false,true><<<B_ROWS, 256, 0, stream>>>(h_x, p1g, p1b, nullptr, tnb_h, tnb_l);
    gemm_split_nt64<true,true,false, false,true, true,true><<<g64(B_ROWS, D_BLOCK), blk, 0, stream>>>(
        tnb_h, tnb_l, p1W1Th, p1W1Tl, p1b1, nullptr, nullptr, tb_h, tb_l, B_ROWS, D_BLOCK, D_MAIN);
    gemm_split_nt64<false,true,true, true,false, true,true><<<g64(B_ROWS, D_MAIN), blk, 0, stream>>>(
        tb_h, tb_l, p1W2Th, p1W2Tl, p1b2, h_x, h_x, nullptr, nullptr, B_ROWS, D_MAIN, D_BLOCK);

    // 8) head (fp32)
    ln_kernel<true,false><<<B_ROWS, 256, 0, stream>>>(h_x, headg, headb, tn_x, nullptr, nullptr);
    gemm_head<<<dim3(1, (B_ROWS + 63) / 64), blk, 0, stream>>>(
        tn_x, head_W, head_bias, (float*)d_out, B_ROWS, N_OUT, D_MAIN);
}

// Round 15
// 981.595 us; speedup vs baseline: 1.0151x; 1.0151x over previous
//
#include <hip/hip_runtime.h>
#include <hip/hip_bf16.h>
#include <cstdint>
#include <cstddef>

#define B_ROWS 1024
#define N_CAND 50000
#define CTX    96
#define D_IN   128
#define D_MAIN 256
#define D_BLOCK 512
#define N_OUT  10
#define LN_EPS 1e-5f
#define MAXTIE 4096
#define TKCAP  8192
#define NTOT   (N_CAND + B_ROWS)

typedef unsigned short u16;
typedef __attribute__((ext_vector_type(8))) short bf16x8;
typedef __attribute__((ext_vector_type(4))) float f32x4;

__device__ __forceinline__ u16 bf16_bits(float f) {
    __hip_bfloat16 h = __float2bfloat16(f);
    return *reinterpret_cast<u16*>(&h);
}
__device__ __forceinline__ float bits_to_f32(u16 b) {
    unsigned u = ((unsigned)b) << 16;
    return __uint_as_float(u);
}
__device__ __forceinline__ void split_f32(float v, u16& h, u16& l) {
    h = bf16_bits(v);
    l = bf16_bits(v - bits_to_f32(h));
}
__device__ __forceinline__ float join_f32(u16 h, u16 l) {
    return bits_to_f32(h) + bits_to_f32(l);
}
__device__ __forceinline__ unsigned f2u_mono(float f) {
    unsigned u = __float_as_uint(f);
    return u ^ ((u & 0x80000000u) ? 0xFFFFFFFFu : 0x80000000u);
}

__device__ __forceinline__ void load_lds_16B(const void* gp, void* lp) {
    __builtin_amdgcn_global_load_lds((const __attribute__((address_space(1))) void*)gp,
                                     (__attribute__((address_space(3))) void*)lp,
                                     16, 0, 0);
}

// ---------------------------------------------------------------------------
// Split-bf16 MFMA GEMM (NT). 128x128 tile, BK=32, 1024 threads (16 waves),
// per-wave output 32x32 (acc 2x2). 16x16x32 MFMA. R10-proven (occ 50%+).
// acc += AhBh (+AlBh if A_LO) (+AhBl if B_LO).
// NOTE (R5+R7): per-K-step global fragment loads are a confirmed
// anti-pattern. NOTE (R3): hand-counted vmcnt pipelines likewise.
// NOTE (R14): 64x64-tile small-M variant for the post chain was neutral.
// KEY16: u16 monotone key of (-2*acc+bias) -> Ch (staged LDS store).
// OUT_SPLIT: (Ch,Cl).  OUT_B16: Ch bf16.  OUT_F32: Cf.  MXFAST: m on blockIdx.x
// MXFAST also applies an XCD-grouping block swizzle (B-panel L2 locality).
// Epilogue LDS tile stride padded 128->136 u16 (bank-conflict fix).
// ---------------------------------------------------------------------------
template<bool RELU, bool HAS_BIAS, bool HAS_RES, bool KEY16,
         bool OUT_F32, bool OUT_SPLIT, bool OUT_B16, bool A_LO, bool B_LO, bool MXFAST>
__global__ __launch_bounds__(1024)
void gemm_split_nt(const u16* __restrict__ Ah, const u16* __restrict__ Al,
                   const u16* __restrict__ Bh, const u16* __restrict__ Bl,
                   const float* __restrict__ bias, const float* __restrict__ Rm,
                   float* __restrict__ Cf, u16* __restrict__ Ch, u16* __restrict__ Cl,
                   int M, int N, int K)
{
    constexpr int nArrA = 1 + (A_LO ? 1 : 0);
    constexpr int nArrB = 1 + (B_LO ? 1 : 0);
    constexpr int NARR  = nArrA + nArrB;
    constexpr int N_LOAD = NARR * 4096;         // u16 per buffer
    constexpr bool STAGED = KEY16 || OUT_SPLIT || OUT_B16;
    constexpr int CS_STRIDE = 136;              // padded epilogue stride
    constexpr int CS_SIZE = 128 * CS_STRIDE;
    constexpr int SM_MIN = STAGED ? CS_SIZE : 0;
    constexpr int SM_U16 = (2 * N_LOAD > SM_MIN) ? 2 * N_LOAD : SM_MIN;
    __shared__ __align__(16) u16 smem[SM_U16];

    constexpr int offAsl = A_LO ? 4096 : 0;
    constexpr int offBsh = 4096 * nArrA;
    constexpr int offBsl = offBsh + (B_LO ? 4096 : 0);

    const int tid  = threadIdx.x;
    const int wave = tid >> 6, lane = tid & 63;

    int bm, bn;
    if constexpr (MXFAST) {
        // XCD-grouping swizzle: blocks sharing a B-panel (same n, all m) land
        // on one XCD for L2 reuse of the streamed B panel.
        const unsigned nbm = gridDim.x;
        const unsigned total = nbm * gridDim.y;
        const unsigned h = blockIdx.x + nbm * blockIdx.y;
        unsigned mi = blockIdx.x, ni = blockIdx.y;
        if ((total & 7u) == 0u) {
            const unsigned per = total >> 3;
            const unsigned virt = (h & 7u) * per + (h >> 3);
            mi = virt % nbm;
            ni = virt / nbm;
        }
        bm = (int)mi * 128; bn = (int)ni * 128;
    } else {
        bm = blockIdx.y * 128; bn = blockIdx.x * 128;
    }

    const int wm = (wave >> 2) * 32, wn = (wave & 3) * 32;
    const int l16 = lane & 15, quad = lane >> 4;

    const int srow = lane >> 2;
    const int scol = (lane & 3) * 8;

    // per-wave staging segments: seg s covers 16 rows x 32 cols of array s>>3
    auto segAddr = [&](int s, const u16*& gp, int& lo) {
        const int a = s >> 3, rb = s & 7;
        const bool isA = (a < nArrA);
        int row = (isA ? bm : bn) + rb * 16 + srow;
        const int mx = (isA ? M : N) - 1;
        if (row > mx) row = mx;
        const u16* base;
        if (a == 0)            base = Ah;
        else if (a == 1)       base = (nArrA > 1) ? Al : Bh;
        else if (a == 2)       base = (nArrA > 1) ? Bh : Bl;
        else                   base = Bl;
        gp = base + (size_t)row * K + scol;
        lo = a * 4096 + rb * 512;
    };

    const u16* sg0; int sl0;
    segAddr(wave, sg0, sl0);
    const u16* sg1 = nullptr; int sl1 = 0;
    constexpr bool SEG1_ALL  = (NARR == 4);
    constexpr bool SEG1_HALF = (NARR == 3);
    if constexpr (SEG1_ALL)  segAddr(wave + 16, sg1, sl1);
    if constexpr (SEG1_HALF) { if (wave < 8) segAddr(wave + 16, sg1, sl1); }

    auto stage = [&](int buf, int k0) {
        u16* base = smem + buf * N_LOAD;
        load_lds_16B(sg0 + k0, &base[sl0]);
        if constexpr (SEG1_ALL)
            load_lds_16B(sg1 + k0, &base[sl1]);
        if constexpr (SEG1_HALF) {
            if (wave < 8) load_lds_16B(sg1 + k0, &base[sl1]);
        }
    };

    f32x4 acc[2][2];
    #pragma unroll
    for (int i = 0; i < 2; ++i)
        #pragma unroll
        for (int j = 0; j < 2; ++j)
            acc[i][j] = (f32x4){0.f, 0.f, 0.f, 0.f};

    stage(0, 0);
    int cur = 0;
    for (int k0 = 0; k0 < K; k0 += 32) {
        __syncthreads();   // drains vmcnt(0): buf[cur] ready; prev reads done

        const u16* Ash = smem + cur * N_LOAD;
        const u16* Asl = Ash + offAsl;
        const u16* Bsh = Ash + offBsh;
        const u16* Bsl = Ash + offBsl;

        bf16x8 ah[2], al[2], bh[2], bl[2];
        #pragma unroll
        for (int i = 0; i < 2; ++i) {
            ah[i] = *(const bf16x8*)&Ash[(wm + i * 16 + l16) * 32 + quad * 8];
            if constexpr (A_LO)
                al[i] = *(const bf16x8*)&Asl[(wm + i * 16 + l16) * 32 + quad * 8];
        }
        #pragma unroll
        for (int j = 0; j < 2; ++j) {
            bh[j] = *(const bf16x8*)&Bsh[(wn + j * 16 + l16) * 32 + quad * 8];
            if constexpr (B_LO)
                bl[j] = *(const bf16x8*)&Bsl[(wn + j * 16 + l16) * 32 + quad * 8];
        }

        if (k0 + 32 < K) stage(cur ^ 1, k0 + 32);   // overlaps with MFMA below

        #pragma unroll
        for (int i = 0; i < 2; ++i)
            #pragma unroll
            for (int j = 0; j < 2; ++j) {
                acc[i][j] = __builtin_amdgcn_mfma_f32_16x16x32_bf16(ah[i], bh[j], acc[i][j], 0, 0, 0);
                if constexpr (A_LO)
                    acc[i][j] = __builtin_amdgcn_mfma_f32_16x16x32_bf16(al[i], bh[j], acc[i][j], 0, 0, 0);
                if constexpr (B_LO)
                    acc[i][j] = __builtin_amdgcn_mfma_f32_16x16x32_bf16(ah[i], bl[j], acc[i][j], 0, 0, 0);
            }
        cur ^= 1;
    }

    float bvj[2];
    #pragma unroll
    for (int j = 0; j < 2; ++j) {
        const int n = bn + wn + j * 16 + l16;
        bvj[j] = ((HAS_BIAS || KEY16) && n < N) ? bias[n] : 0.f;
    }
    auto compute = [&](int i, int j, int r) -> float {
        float v = acc[i][j][r];
        if (KEY16) return -2.f * v + bvj[j];
        if (HAS_BIAS) v += bvj[j];
        if (RELU)     v = fmaxf(v, 0.f);
        if (HAS_RES) {
            const int n = bn + wn + j * 16 + l16;
            const int m = bm + wm + i * 16 + quad * 4 + r;
            v += Rm[(size_t)m * N + n];
        }
        return v;
    };

    if constexpr (OUT_F32) {
        #pragma unroll
        for (int j = 0; j < 2; ++j) {
            const int n = bn + wn + j * 16 + l16;
            if (n >= N) continue;
            #pragma unroll
            for (int i = 0; i < 2; ++i)
                #pragma unroll
                for (int r = 0; r < 4; ++r) {
                    const int m = bm + wm + i * 16 + quad * 4 + r;
                    if (m >= M) continue;
                    Cf[(size_t)m * N + n] = compute(i, j, r);
                }
        }
    }

    if constexpr (STAGED) {
        u16* Cs = smem;
        const int phases = OUT_SPLIT ? 2 : 1;
        for (int ph = 0; ph < phases; ++ph) {
            __syncthreads();
            #pragma unroll
            for (int j = 0; j < 2; ++j) {
                const int nl = wn + j * 16 + l16;
                if (bn + nl >= N) continue;
                #pragma unroll
                for (int i = 0; i < 2; ++i)
                    #pragma unroll
                    for (int r = 0; r < 4; ++r) {
                        const int ml = wm + i * 16 + quad * 4 + r;
                        if (bm + ml >= M) continue;
                        const float v = compute(i, j, r);
                        u16 out;
                        if (KEY16)        out = (u16)(f2u_mono(v) >> 16);
                        else if (OUT_B16) out = bf16_bits(v);
                        else { u16 h, l; split_f32(v, h, l); out = ph ? l : h; }
                        Cs[ml * CS_STRIDE + nl] = out;
                    }
            }
            __syncthreads();
            u16* dstB = (OUT_SPLIT && ph) ? Cl : Ch;
            const int row = tid >> 3, seg = (tid & 7) * 16;
            const int m = bm + row;
            if (m < M) {
                const int ncols = N - bn;
                u16* dst = dstB + (size_t)m * N + bn + seg;
                const u16* srcp = &Cs[row * CS_STRIDE + seg];
                if (ncols >= 128) {
                    #pragma unroll
                    for (int c = 0; c < 2; ++c)
                        *reinterpret_cast<uint4*>(dst + c * 8) =
                            *reinterpret_cast<const uint4*>(srcp + c * 8);
                } else {
                    for (int e = 0; e < 16; ++e)
                        if (seg + e < ncols) dst[e] = srcp[e];
                }
            }
        }
    }
}

// ---------------------------------------------------------------------------
// Small-N fp32 GEMM (head, N=10)
// ---------------------------------------------------------------------------
__global__ __launch_bounds__(256)
void gemm_head(const float* __restrict__ A, const float* __restrict__ Bm,
               const float* __restrict__ bias, float* __restrict__ C,
               int M, int N, int K)
{
    __shared__ float As[16][64];
    __shared__ float Bs[16][64];
    const int tid = threadIdx.x;
    const int bm = blockIdx.y * 64;

    const int a_m = tid >> 2;
    const int a_k = (tid & 3) << 2;
    const int b_k = tid >> 4;
    const int b_n = (tid & 15) << 2;
    const int my = (tid >> 4) << 2;
    const int nx = (tid & 15) << 2;

    float acc[4][4] = {};

    for (int k0 = 0; k0 < K; k0 += 16) {
        float4 av = make_float4(0.f,0.f,0.f,0.f);
        const int gm = bm + a_m;
        if (gm < M) av = *(const float4*)(A + (size_t)gm * K + k0 + a_k);
        As[a_k+0][a_m]=av.x; As[a_k+1][a_m]=av.y; As[a_k+2][a_m]=av.z; As[a_k+3][a_m]=av.w;

        float4 bv = make_float4(0.f,0.f,0.f,0.f);
        const float* bp = Bm + (size_t)(k0 + b_k) * N + b_n;
        if (b_n + 0 < N) bv.x = bp[0];
        if (b_n + 1 < N) bv.y = bp[1];
        if (b_n + 2 < N) bv.z = bp[2];
        if (b_n + 3 < N) bv.w = bp[3];
        *(float4*)&Bs[b_k][b_n] = bv;

        __syncthreads();
        #pragma unroll
        for (int k = 0; k < 16; ++k) {
            const float4 a4 = *(const float4*)&As[k][my];
            const float4 b4 = *(const float4*)&Bs[k][nx];
            const float a[4] = {a4.x,a4.y,a4.z,a4.w};
            const float b[4] = {b4.x,b4.y,b4.z,b4.w};
            #pragma unroll
            for (int i = 0; i < 4; ++i)
                #pragma unroll
                for (int j = 0; j < 4; ++j)
                    acc[i][j] = fmaf(a[i], b[j], acc[i][j]);
        }
        __syncthreads();
    }

    #pragma unroll
    for (int i = 0; i < 4; ++i) {
        const int m = bm + my + i;
        if (m >= M) continue;
        #pragma unroll
        for (int j = 0; j < 4; ++j) {
            const int n = nx + j;
            if (n >= N) continue;
            C[(size_t)m * N + n] = acc[i][j] + bias[n];
        }
    }
}

// ---------------------------------------------------------------------------
// LayerNorm over 256 cols; fp32 input; OUT_SPLIT -> (Yh,Yl) else Yf f32.
// ---------------------------------------------------------------------------
template<bool RELU, bool OUT_SPLIT>
__global__ __launch_bounds__(256)
void ln_kernel(const float* __restrict__ X, const float* __restrict__ g,
               const float* __restrict__ b, float* __restrict__ Yf,
               u16* __restrict__ Yh, u16* __restrict__ Yl)
{
    const int row = blockIdx.x, tid = threadIdx.x;
    const float x = X[(size_t)row * D_MAIN + tid];
    __shared__ float red[4];
    const int lane = tid & 63, wid = tid >> 6;

    float s = x;
    #pragma unroll
    for (int off = 32; off; off >>= 1) s += __shfl_down(s, off, 64);
    if (lane == 0) red[wid] = s;
    __syncthreads();
    const float mean = (red[0] + red[1] + red[2] + red[3]) * (1.f / D_MAIN);
    __syncthreads();

    const float xm = x - mean;
    s = xm * xm;
    #pragma unroll
    for (int off = 32; off; off >>= 1) s += __shfl_down(s, off, 64);
    if (lane == 0) red[wid] = s;
    __syncthreads();
    const float var = (red[0] + red[1] + red[2] + red[3]) * (1.f / D_MAIN);

    float y = xm / sqrtf(var + LN_EPS) * g[tid] + b[tid];
    if (RELU) y = fmaxf(y, 0.f);
    if (OUT_SPLIT) {
        u16 h, l; split_f32(y, h, l);
        Yh[(size_t)row * D_MAIN + tid] = h;
        Yl[(size_t)row * D_MAIN + tid] = l;
    } else {
        Yf[(size_t)row * D_MAIN + tid] = y;
    }
}

// ---------------------------------------------------------------------------
// ||cand_k[n]||^2 from split
// ---------------------------------------------------------------------------
__global__ __launch_bounds__(64)
void cn2_kernel(const u16* __restrict__ ckh, const u16* __restrict__ ckl,
                float* __restrict__ out)
{
    const int row = blockIdx.x, lane = threadIdx.x;
    const ushort4 h4 = *(const ushort4*)(ckh + (size_t)row * D_MAIN + lane * 4);
    const ushort4 l4 = *(const ushort4*)(ckl + (size_t)row * D_MAIN + lane * 4);
    const float c0 = join_f32(h4.x, l4.x), c1 = join_f32(h4.y, l4.y);
    const float c2 = join_f32(h4.z, l4.z), c3 = join_f32(h4.w, l4.w);
    float s = c0*c0 + c1*c1 + c2*c2 + c3*c3;
    #pragma unroll
    for (int off = 32; off; off >>= 1) s += __shfl_down(s, off, 64);
    if (lane == 0) out[row] = s;
}

// ---------------------------------------------------------------------------
// conversions
// ---------------------------------------------------------------------------
__global__ __launch_bounds__(256)
void f32_to_split_kernel(const float* __restrict__ src, u16* __restrict__ hi,
                         u16* __restrict__ lo, int n)
{
    int i = blockIdx.x * 256 + threadIdx.x;
    if (i < n) {
        u16 h, l; split_f32(src[i], h, l);
        hi[i] = h; lo[i] = l;
    }
}

struct TrD { const float* s; u16* dh; u16* dl; int R; int C; };
struct TrDs { TrD d[11]; };

__global__ __launch_bounds__(256)
void transpose_all_kernel(TrDs descs)
{
    const TrD D = descs.d[blockIdx.y];
    const int n = D.R * D.C;
    int idx = blockIdx.x * 256 + threadIdx.x;
    if (idx < n) {
        const int r = idx / D.C, c = idx % D.C;
        u16 h, l; split_f32(D.s[idx], h, l);
        D.dh[(size_t)c * D.R + r] = h;
        D.dl[(size_t)c * D.R + r] = l;
    }
}

__global__ __launch_bounds__(256)
void copy_rows_kernel(const float* __restrict__ src, float* __restrict__ dst, int n)
{
    int i = blockIdx.x * 256 + threadIdx.x;
    if (i < n) dst[i] = src[i];
}

// ---------------------------------------------------------------------------
// Top-96 smallest per row on u16 keys — 2-pass + candidate list (R11/R13-
// proven best). Plain per-lane LDS atomics: R12 measured wave-aggregated
// returning atomics NET-NEGATIVE here (ballot/shfl/popc overhead per call
// exceeds the serialization it removes at this predicate density).
// Pass 1: high-byte histogram -> boundary bin hb. Pass 2: low-byte hist
// within hb + collect (lowbyte,idx) candidates + emit hb'<hb directly.
// Pass 3 scans only the candidate list; overflow falls back to full hb-bin
// scan. Selection set identical to the 3-pass version (same T16 partition).
// ---------------------------------------------------------------------------
__global__ __launch_bounds__(1024)
void topk96_u16_kernel(const u16* __restrict__ keys, int* __restrict__ idx_out,
                       int* __restrict__ tiebuf, int* __restrict__ tiecnt,
                       int* __restrict__ lesscnt, unsigned* __restrict__ candbuf)
{
    const int row = blockIdx.x;
    const u16* krow = keys + (size_t)row * N_CAND;
    unsigned* cand = candbuf + (size_t)row * TKCAP;
    const int tid = threadIdx.x;
    const int rep = tid & 63;

    __shared__ unsigned hist[256 * 64];
    __shared__ unsigned hsum[256];
    __shared__ unsigned sh_bin, sh_need;
    __shared__ int cntLess, cntEq, candCnt;

    // ---- pass 1: high-byte histogram ----
    #pragma unroll
    for (int i = 0; i < 16; ++i) hist[tid + i * 1024] = 0;
    __syncthreads();
    for (int i = tid; i < N_CAND / 8; i += 1024) {
        const uint4 v = ((const uint4*)krow)[i];
        const unsigned w[4] = {v.x, v.y, v.z, v.w};
        #pragma unroll
        for (int e = 0; e < 4; ++e) {
            atomicAdd(&hist[(((w[e] >> 8) & 0xFFu)) * 64 + rep], 1u);
            atomicAdd(&hist[((w[e] >> 24)) * 64 + rep], 1u);
        }
    }
    __syncthreads();
    if (tid < 256) {
        unsigned s = 0;
        #pragma unroll
        for (int r = 0; r < 64; ++r) s += hist[tid * 64 + ((r + tid) & 63)];
        hsum[tid] = s;
    }
    __syncthreads();
    int need = CTX;
    if (tid < 64) {
        const unsigned b0 = hsum[tid*4+0], b1 = hsum[tid*4+1],
                       b2 = hsum[tid*4+2], b3 = hsum[tid*4+3];
        const unsigned lsum = b0 + b1 + b2 + b3;
        unsigned pre = lsum;
        #pragma unroll
        for (int off = 1; off < 64; off <<= 1) {
            const unsigned t = __shfl_up(pre, off, 64);
            if (tid >= off) pre += t;
        }
        const unsigned excl = pre - lsum;
        const unsigned nd = (unsigned)need;
        if (excl < nd && excl + lsum >= nd) {
            unsigned bin, rem;
            if      (excl + b0 >= nd)           { bin = tid*4+0; rem = nd - excl; }
            else if (excl + b0 + b1 >= nd)      { bin = tid*4+1; rem = nd - excl - b0; }
            else if (excl + b0 + b1 + b2 >= nd) { bin = tid*4+2; rem = nd - excl - b0 - b1; }
            else                                { bin = tid*4+3; rem = nd - excl - b0 - b1 - b2; }
            sh_bin = bin; sh_need = rem;
        }
    }
    __syncthreads();
    const unsigned hb = sh_bin;
    need = (int)sh_need;
    __syncthreads();

    // ---- pass 2: low-byte hist within hb + emit less + collect candidates ----
    #pragma unroll
    for (int i = 0; i < 16; ++i) hist[tid + i * 1024] = 0;
    if (tid == 0) { cntLess = 0; cntEq = 0; candCnt = 0; }
    __syncthreads();
    for (int i = tid; i < N_CAND / 8; i += 1024) {
        const uint4 v = ((const uint4*)krow)[i];
        const unsigned w[4] = {v.x, v.y, v.z, v.w};
        #pragma unroll
        for (int e = 0; e < 4; ++e) {
            const unsigned k0 = w[e] & 0xFFFFu, k1 = w[e] >> 16;
            const int n0 = i * 8 + e * 2, n1 = n0 + 1;
            const unsigned h0 = k0 >> 8, h1 = k1 >> 8;
            if (h0 == hb) {
                atomicAdd(&hist[(k0 & 255u) * 64 + rep], 1u);
                const int p = atomicAdd(&candCnt, 1);
                if (p < TKCAP) cand[p] = ((k0 & 255u) << 16) | (unsigned)n0;
            } else if (h0 < hb) {
                const int p = atomicAdd(&cntLess, 1);
                idx_out[row * CTX + p] = n0;
            }
            if (h1 == hb) {
                atomicAdd(&hist[(k1 & 255u) * 64 + rep], 1u);
                const int p = atomicAdd(&candCnt, 1);
                if (p < TKCAP) cand[p] = ((k1 & 255u) << 16) | (unsigned)n1;
            } else if (h1 < hb) {
                const int p = atomicAdd(&cntLess, 1);
                idx_out[row * CTX + p] = n1;
            }
        }
    }
    __syncthreads();
    if (tid < 256) {
        unsigned s = 0;
        #pragma unroll
        for (int r = 0; r < 64; ++r) s += hist[tid * 64 + ((r + tid) & 63)];
        hsum[tid] = s;
    }
    __syncthreads();
    if (tid < 64) {
        const unsigned b0 = hsum[tid*4+0], b1 = hsum[tid*4+1],
                       b2 = hsum[tid*4+2], b3 = hsum[tid*4+3];
        const unsigned lsum = b0 + b1 + b2 + b3;
        unsigned pre = lsum;
        #pragma unroll
        for (int off = 1; off < 64; off <<= 1) {
            const unsigned t = __shfl_up(pre, off, 64);
            if (tid >= off) pre += t;
        }
        const unsigned excl = pre - lsum;
        const unsigned nd = (unsigned)need;
        if (excl < nd && excl + lsum >= nd) {
            unsigned bin, rem;
            if      (excl + b0 >= nd)           { bin = tid*4+0; rem = nd - excl; }
            else if (excl + b0 + b1 >= nd)      { bin = tid*4+1; rem = nd - excl - b0; }
            else if (excl + b0 + b1 + b2 >= nd) { bin = tid*4+2; rem = nd - excl - b0 - b1; }
            else                                { bin = tid*4+3; rem = nd - excl - b0 - b1 - b2; }
            sh_bin = bin; sh_need = rem;
        }
    }
    __syncthreads();
    const unsigned lb = sh_bin;
    const int CC = candCnt;
    __syncthreads();

    // ---- pass 3: candidate scan (tiny) or fallback full hb-bin scan ----
    if (CC <= TKCAP) {
        for (int t = tid; t < CC; t += 1024) {
            const unsigned e = cand[t];
            const unsigned l8 = e >> 16;
            const int n = (int)(e & 0xFFFFu);
            if (l8 < lb) {
                const int p = atomicAdd(&cntLess, 1);
                idx_out[row * CTX + p] = n;
            } else if (l8 == lb) {
                const int p = atomicAdd(&cntEq, 1);
                if (p < MAXTIE) tiebuf[(size_t)row * MAXTIE + p] = n;
            }
        }
    } else {
        for (int i = tid; i < N_CAND / 8; i += 1024) {
            const uint4 v = ((const uint4*)krow)[i];
            const unsigned w[4] = {v.x, v.y, v.z, v.w};
            #pragma unroll
            for (int e = 0; e < 4; ++e) {
                const unsigned k0 = w[e] & 0xFFFFu, k1 = w[e] >> 16;
                const int n0 = i * 8 + e * 2, n1 = n0 + 1;
                if ((k0 >> 8) == hb) {
                    const unsigned l8 = k0 & 255u;
                    if (l8 < lb) {
                        const int p = atomicAdd(&cntLess, 1);
                        idx_out[row * CTX + p] = n0;
                    } else if (l8 == lb) {
                        const int p = atomicAdd(&cntEq, 1);
                        if (p < MAXTIE) tiebuf[(size_t)row * MAXTIE + p] = n0;
                    }
                }
                if ((k1 >> 8) == hb) {
                    const unsigned l8 = k1 & 255u;
                    if (l8 < lb) {
                        const int p = atomicAdd(&cntLess, 1);
                        idx_out[row * CTX + p] = n1;
                    } else if (l8 == lb) {
                        const int p = atomicAdd(&cntEq, 1);
                        if (p < MAXTIE) tiebuf[(size_t)row * MAXTIE + p] = n1;
                    }
                }
            }
        }
    }
    __syncthreads();
    if (tid == 0) {
        lesscnt[row] = cntLess;
        tiecnt[row] = (cntEq < MAXTIE) ? cntEq : MAXTIE;
    }
}

// ---------------------------------------------------------------------------
// Fused: exact fp32 tie-break + exact sval for selected 96 + softmax.
// Latency-optimized (R4-proven): MLP-unrolled tie dots, 64-lane parallel bin
// scan, 4-deep pipelined sval gathers, single-wave shfl softmax.
// ---------------------------------------------------------------------------
__global__ __launch_bounds__(256)
void select_kernel(const u16* __restrict__ kh, const u16* __restrict__ kl,
                   const u16* __restrict__ ckh, const u16* __restrict__ ckl,
                   const float* __restrict__ ck2,
                   const int* __restrict__ tiebuf, const int* __restrict__ tiecnt,
                   const int* __restrict__ lesscnt,
                   int* __restrict__ idx_out, float* __restrict__ probs)
{
    const int row = blockIdx.x;
    const int tid = threadIdx.x;
    const int T = tiecnt[row];
    const int less = lesscnt[row];
    const int need = CTX - less;

    __shared__ float kvs[D_MAIN];
    __shared__ int   sel[CTX];
    __shared__ float svals[CTX];
    __shared__ float sv[MAXTIE];
    __shared__ unsigned hist[256];
    __shared__ unsigned sh_bin, sh_need;
    __shared__ int c1, c2;

    if (tid < D_MAIN)
        kvs[tid] = join_f32(kh[(size_t)row * D_MAIN + tid], kl[(size_t)row * D_MAIN + tid]);
    if (tid < CTX && tid < less) sel[tid] = idx_out[row * CTX + tid];
    __syncthreads();

    if (T <= need) {
        for (int t = tid; t < T; t += 256) {
            sel[less + t] = tiebuf[(size_t)row * MAXTIE + t];
            idx_out[row * CTX + less + t] = sel[less + t];
        }
    } else {
        for (int t = tid; t < T; t += 256) {
            const int c = tiebuf[(size_t)row * MAXTIE + t];
            const u16* ch = ckh + (size_t)c * D_MAIN;
            const u16* cl = ckl + (size_t)c * D_MAIN;
            float s = 0.f;
            #pragma unroll 8
            for (int d = 0; d < D_MAIN; d += 4) {
                const ushort4 h4 = *(const ushort4*)(ch + d);
                const ushort4 l4 = *(const ushort4*)(cl + d);
                s += kvs[d+0] * join_f32(h4.x, l4.x) + kvs[d+1] * join_f32(h4.y, l4.y)
                   + kvs[d+2] * join_f32(h4.z, l4.z) + kvs[d+3] * join_f32(h4.w, l4.w);
            }
            sv[t] = ck2[c] - 2.f * s;
        }
        __syncthreads();

        unsigned prefix = 0;
        int plen = 0;
        int nd = need;
        for (int pass = 0; pass < 4; ++pass) {
            const int shift = 24 - 8 * pass;
            hist[tid] = 0;
            __syncthreads();
            for (int t = tid; t < T; t += 256) {
                const unsigned u = f2u_mono(sv[t]);
                if (plen == 0 || (u >> (32 - plen)) == prefix)
                    atomicAdd(&hist[(u >> shift) & 255u], 1u);
            }
            __syncthreads();
            if (tid < 64) {   // parallel 256-bin boundary scan (64-lane prefix)
                const unsigned b0 = hist[tid*4+0], b1 = hist[tid*4+1],
                               b2 = hist[tid*4+2], b3 = hist[tid*4+3];
                const unsigned lsum = b0 + b1 + b2 + b3;
                unsigned pre = lsum;
                #pragma unroll
                for (int off = 1; off < 64; off <<= 1) {
                    const unsigned tt = __shfl_up(pre, off, 64);
                    if (tid >= off) pre += tt;
                }
                const unsigned excl = pre - lsum;
                const unsigned ndu = (unsigned)nd;
                if (excl < ndu && excl + lsum >= ndu) {
                    unsigned bin, rem;
                    if      (excl + b0 >= ndu)           { bin = tid*4+0; rem = ndu - excl; }
                    else if (excl + b0 + b1 >= ndu)      { bin = tid*4+1; rem = ndu - excl - b0; }
                    else if (excl + b0 + b1 + b2 >= ndu) { bin = tid*4+2; rem = ndu - excl - b0 - b1; }
                    else                                 { bin = tid*4+3; rem = ndu - excl - b0 - b1 - b2; }
                    sh_bin = bin; sh_need = rem;
                }
            }
            __syncthreads();
            prefix = (prefix << 8) | sh_bin;
            nd = (int)sh_need;
            plen += 8;
            __syncthreads();
        }
        const unsigned Tf = prefix;
        const int nl2 = need - nd;
        if (tid == 0) { c1 = 0; c2 = 0; }
        __syncthreads();
        for (int t = tid; t < T; t += 256) {
            const unsigned u = f2u_mono(sv[t]);
            if (u < Tf) {
                const int p = atomicAdd(&c1, 1);
                sel[less + p] = tiebuf[(size_t)row * MAXTIE + t];
                idx_out[row * CTX + less + p] = sel[less + p];
            } else if (u == Tf) {
                const int p = atomicAdd(&c2, 1);
                if (p < nd) {
                    sel[less + nl2 + p] = tiebuf[(size_t)row * MAXTIE + t];
                    idx_out[row * CTX + less + nl2 + p] = sel[less + nl2 + p];
                }
            }
        }
    }
    __syncthreads();

    // exact sval for selected 96: 4 rows in flight per wave (MLP)
    const int wv = tid >> 6, lane = tid & 63;
    #pragma unroll
    for (int k = 0; k < 24; k += 4) {
        int ids[4];
        ushort4 h4[4], l4[4];
        #pragma unroll
        for (int u = 0; u < 4; ++u) {
            const int c = wv + 4 * (k + u);
            ids[u] = sel[c];
            h4[u] = *(const ushort4*)(ckh + (size_t)ids[u] * D_MAIN + lane * 4);
            l4[u] = *(const ushort4*)(ckl + (size_t)ids[u] * D_MAIN + lane * 4);
        }
        #pragma unroll
        for (int u = 0; u < 4; ++u) {
            const int c = wv + 4 * (k + u);
            float s = kvs[lane*4+0] * join_f32(h4[u].x, l4[u].x)
                    + kvs[lane*4+1] * join_f32(h4[u].y, l4[u].y)
                    + kvs[lane*4+2] * join_f32(h4[u].z, l4[u].z)
                    + kvs[lane*4+3] * join_f32(h4[u].w, l4[u].w);
            #pragma unroll
            for (int off = 32; off; off >>= 1) s += __shfl_down(s, off, 64);
            if (lane == 0) svals[c] = ck2[ids[u]] - 2.f * s;
        }
    }
    __syncthreads();

    // softmax over 96 in one wave (no barriers)
    if (tid < 64) {
        const float a = -svals[tid];
        const float b = (tid < 32) ? -svals[64 + tid] : -1e30f;
        float m = fmaxf(a, b);
        #pragma unroll
        for (int off = 32; off; off >>= 1) m = fmaxf(m, __shfl_xor(m, off, 64));
        const float ea = __expf(a - m);
        const float eb = (tid < 32) ? __expf(b - m) : 0.f;
        float ssum = ea + eb;
        #pragma unroll
        for (int off = 32; off; off >>= 1) ssum += __shfl_xor(ssum, off, 64);
        const float inv = 1.f / ssum;
        probs[row * CTX + tid] = ea * inv;
        if (tid < 32) probs[row * CTX + 64 + tid] = eb * inv;
    }
}

// ---------------------------------------------------------------------------
// Fused T-MLP collapse via linearity of W1 AND W2:
//   relu((k_b - ck_c)@W1 + b1) = relu(Q[N_CAND+b] + b1 - Q[id_c])
//   u[b]  = sum_c p_c * relu(...)              (512 cols, fp32, kept in LDS)
//   h[b] += sum_c p_c * label_emb[cy[id_c]]  + u[b] @ T_W2   (all fp32)
// ---------------------------------------------------------------------------
__global__ __launch_bounds__(256)
void tmix_kernel(const float* __restrict__ Q, const float* __restrict__ b1,
                 const float* __restrict__ W2, const float* __restrict__ probs,
                 const int* __restrict__ idx, const int* __restrict__ cy,
                 const float* __restrict__ label_emb, float* __restrict__ h)
{
    const int b = blockIdx.x, tid = threadIdx.x;
    __shared__ float pr[CTX];
    __shared__ int   ids[CTX];
    __shared__ int   labs[CTX];
    __shared__ float lemb[N_OUT * D_MAIN];
    __shared__ float uv[D_BLOCK];
    if (tid < CTX) {
        const int id = idx[b * CTX + tid];
        ids[tid]  = id;
        pr[tid]   = probs[b * CTX + tid];
        labs[tid] = cy[id];
    }
    for (int i = tid; i < N_OUT * D_MAIN; i += 256) lemb[i] = label_emb[i];
    __syncthreads();

    const int j0 = tid * 2;
    const float2 pb = *(const float2*)(Q + (size_t)(N_CAND + b) * D_BLOCK + j0);
    const float p0 = pb.x + b1[j0];
    const float p1 = pb.y + b1[j0 + 1];
    float a0 = 0.f, a1 = 0.f, ahd = 0.f;
    #pragma unroll 4
    for (int c = 0; c < CTX; ++c) {
        const float p = pr[c];
        const float2 q = *(const float2*)(Q + (size_t)ids[c] * D_BLOCK + j0);
        a0  = fmaf(p, fmaxf(p0 - q.x, 0.f), a0);
        a1  = fmaf(p, fmaxf(p1 - q.y, 0.f), a1);
        ahd = fmaf(p, lemb[labs[c] * D_MAIN + tid], ahd);
    }
    uv[j0] = a0;
    uv[j0 + 1] = a1;
    __syncthreads();

    // out[tid] = ahd + sum_k uv[k] * W2[k][tid]   (W2 row reads coalesced)
    float o = ahd;
    #pragma unroll 8
    for (int k = 0; k < D_BLOCK; ++k)
        o = fmaf(uv[k], W2[(size_t)k * D_MAIN + tid], o);
    h[(size_t)b * D_MAIN + tid] += o;
}

// ---------------------------------------------------------------------------
// host-side orchestration
// ---------------------------------------------------------------------------
static inline dim3 g128(int M, int N) {
    return dim3((unsigned)((N + 127) / 128), (unsigned)((M + 127) / 128));
}

struct EncW {
    const u16 *WlinTh, *WlinTl, *e0W1Th, *e0W1Tl, *e0W2Th, *e0W2Tl,
              *e1W1Th, *e1W1Tl, *e1W2Th, *e1W2Tl, *KWTh, *KWTl;
    const float *b_lin, *e0b1, *e0b2, *e1g, *e1b, *e1b1, *e1b2, *mixg, *mixb, *Kb;
};

// encoder: fp32 H stream + split activations, split weights (3 MFMA)
static void encode_rows_split(const u16* Xh, const u16* Xl, int R, const EncW& w,
                              float* H, u16* Hh, u16* Hl, u16* Th, u16* Tl,
                              u16* TNh, u16* TNl, u16* Kh, u16* Kl,
                              hipStream_t stream)
{
    dim3 blk(1024);
    gemm_split_nt<false,true,false,false, true,true,false, true,true,false><<<g128(R, D_MAIN), blk, 0, stream>>>(
        Xh, Xl, w.WlinTh, w.WlinTl, w.b_lin, nullptr, H, Hh, Hl, R, D_MAIN, D_IN);
    gemm_split_nt<true,true,false,false, false,true,false, true,true,false><<<g128(R, D_BLOCK), blk, 0, stream>>>(
        Hh, Hl, w.e0W1Th, w.e0W1Tl, w.e0b1, nullptr, nullptr, Th, Tl, R, D_BLOCK, D_MAIN);
    gemm_split_nt<false,true,true,false, true,false,false, true,true,false><<<g128(R, D_MAIN), blk, 0, stream>>>(
        Th, Tl, w.e0W2Th, w.e0W2Tl, w.e0b2, H, H, nullptr, nullptr, R, D_MAIN, D_BLOCK);
    ln_kernel<false,true><<<R, 256, 0, stream>>>(H, w.e1g, w.e1b, nullptr, TNh, TNl);
    gemm_split_nt<true,true,false,false, false,true,false, true,true,false><<<g128(R, D_BLOCK), blk, 0, stream>>>(
        TNh, TNl, w.e1W1Th, w.e1W1Tl, w.e1b1, nullptr, nullptr, Th, Tl, R, D_BLOCK, D_MAIN);
    gemm_split_nt<false,true,true,false, true,false,false, true,true,false><<<g128(R, D_MAIN), blk, 0, stream>>>(
        Th, Tl, w.e1W2Th, w.e1W2Tl, w.e1b2, H, H, nullptr, nullptr, R, D_MAIN, D_BLOCK);
    ln_kernel<false,true><<<R, 256, 0, stream>>>(H, w.mixg, w.mixb, nullptr, TNh, TNl);
    gemm_split_nt<false,true,false,false, false,true,false, true,true,false><<<g128(R, D_MAIN), blk, 0, stream>>>(
        TNh, TNl, w.KWTh, w.KWTl, w.Kb, nullptr, nullptr, Kh, Kl, R, D_MAIN, D_MAIN);
}

extern "C" void kernel_launch(void* const* d_in, const int* in_sizes, int n_in,
                              void* d_out, int out_size, void* d_ws, size_t ws_size,
                              hipStream_t stream)
{
    const float* x        = (const float*)d_in[0];
    const float* cand_x   = (const float*)d_in[1];
    const int*   cand_y   = (const int*)  d_in[2];
    const float* W_lin    = (const float*)d_in[4];
    const float* b_lin    = (const float*)d_in[5];
    const float* e0W1     = (const float*)d_in[6];
    const float* e0b1     = (const float*)d_in[7];
    const float* e0W2     = (const float*)d_in[8];
    const float* e0b2     = (const float*)d_in[9];
    const float* e1g      = (const float*)d_in[10];
    const float* e1b      = (const float*)d_in[11];
    const float* e1W1     = (const float*)d_in[12];
    const float* e1b1     = (const float*)d_in[13];
    const float* e1W2     = (const float*)d_in[14];
    const float* e1b2     = (const float*)d_in[15];
    const float* mixg     = (const float*)d_in[16];
    const float* mixb     = (const float*)d_in[17];
    const float* K_W      = (const float*)d_in[18];
    const float* K_b      = (const float*)d_in[19];
    const float* label_emb= (const float*)d_in[20];
    const float* T_W1     = (const float*)d_in[21];
    const float* T_b1     = (const float*)d_in[22];
    const float* T_W2     = (const float*)d_in[23];
    const float* p0g      = (const float*)d_in[24];
    const float* p0b      = (const float*)d_in[25];
    const float* p0W1     = (const float*)d_in[26];
    const float* p0b1     = (const float*)d_in[27];
    const float* p0W2     = (const float*)d_in[28];
    const float* p0b2     = (const float*)d_in[29];
    const float* p1g      = (const float*)d_in[30];
    const float* p1b      = (const float*)d_in[31];
    const float* p1W1     = (const float*)d_in[32];
    const float* p1b1     = (const float*)d_in[33];
    const float* p1W2     = (const float*)d_in[34];
    const float* p1b2     = (const float*)d_in[35];
    const float* headg    = (const float*)d_in[36];
    const float* headb    = (const float*)d_in[37];
    const float* head_W   = (const float*)d_in[38];
    const float* head_bias= (const float*)d_in[39];

    char* ws = (char*)d_ws;
    size_t off = 0;
    auto alloc = [&](size_t bytes) -> char* {
        char* p = ws + off;
        off += (bytes + 255) & ~(size_t)255;
        return p;
    };

    u16* in_h   = (u16*)alloc((size_t)NTOT * D_IN * 2);
    u16* in_l   = (u16*)alloc((size_t)NTOT * D_IN * 2);
    u16* allk_h = (u16*)alloc((size_t)NTOT * D_MAIN * 2);
    u16* allk_l = (u16*)alloc((size_t)NTOT * D_MAIN * 2);
    float* ck2  = (float*)alloc((size_t)N_CAND * 4);
    float* h_x  = (float*)alloc((size_t)B_ROWS * D_MAIN * 4);
    float* tn_x = (float*)alloc((size_t)B_ROWS * D_MAIN * 4);
    u16* tnb_h  = (u16*)alloc((size_t)B_ROWS * D_MAIN * 2);
    u16* tnb_l  = (u16*)alloc((size_t)B_ROWS * D_MAIN * 2);
    u16* tb_h   = (u16*)alloc((size_t)B_ROWS * D_BLOCK * 2);
    u16* tb_l   = (u16*)alloc((size_t)B_ROWS * D_BLOCK * 2);
    int*   idx  = (int*)  alloc((size_t)B_ROWS * CTX * 4);
    float* probs= (float*)alloc((size_t)B_ROWS * CTX * 4);
    int* tiecnt = (int*)  alloc((size_t)B_ROWS * 4);
    int* lesscnt= (int*)  alloc((size_t)B_ROWS * 4);

    auto allocW = [&](int R, int C, u16** h, u16** l) {
        *h = (u16*)alloc((size_t)R * C * 2);
        *l = (u16*)alloc((size_t)R * C * 2);
    };
    u16 *WlinTh, *WlinTl, *e0W1Th, *e0W1Tl, *e0W2Th, *e0W2Tl,
        *e1W1Th, *e1W1Tl, *e1W2Th, *e1W2Tl, *KWTh, *KWTl,
        *TW1Th, *TW1Tl,
        *p0W1Th, *p0W1Tl, *p0W2Th, *p0W2Tl, *p1W1Th, *p1W1Tl, *p1W2Th, *p1W2Tl;
    allocW(D_IN,   D_MAIN, &WlinTh, &WlinTl);
    allocW(D_MAIN, D_BLOCK,&e0W1Th, &e0W1Tl);
    allocW(D_BLOCK,D_MAIN, &e0W2Th, &e0W2Tl);
    allocW(D_MAIN, D_BLOCK,&e1W1Th, &e1W1Tl);
    allocW(D_BLOCK,D_MAIN, &e1W2Th, &e1W2Tl);
    allocW(D_MAIN, D_MAIN, &KWTh,   &KWTl);
    allocW(D_MAIN, D_BLOCK,&TW1Th,  &TW1Tl);
    allocW(D_MAIN, D_BLOCK,&p0W1Th, &p0W1Tl);
    allocW(D_BLOCK,D_MAIN, &p0W2Th, &p0W2Tl);
    allocW(D_MAIN, D_BLOCK,&p1W1Th, &p1W1Tl);
    allocW(D_BLOCK,D_MAIN, &p1W2Th, &p1W2Tl);

    // tiebuf last among fixed allocs: Q (NTOT x 512 fp32, ~99.7 MiB) overlays
    // tiebuf (dead after select_kernel) and extends into the pool.
    int* tiebuf = (int*)alloc((size_t)B_ROWS * MAXTIE * 4);

    u16* k_x_h = allk_h + (size_t)N_CAND * D_MAIN;
    u16* k_x_l = allk_l + (size_t)N_CAND * D_MAIN;
    u16* x_in_h = in_h + (size_t)N_CAND * D_IN;
    u16* x_in_l = in_l + (size_t)N_CAND * D_IN;

    const size_t pool_avail = (ws_size > off) ? (ws_size - off) : 0;
    int rc_enc = (int)(pool_avail / 5120);
    if (rc_enc > NTOT) rc_enc = NTOT;
    if (rc_enc < 6250) rc_enc = 6250;
    // per-row: keys (2*N_CAND bytes) + candidate buffer (4*TKCAP bytes)
    int mb_ch = (int)(pool_avail / ((size_t)2 * N_CAND + 4 * TKCAP));
    if (mb_ch > B_ROWS) mb_ch = B_ROWS;
    mb_ch &= ~127;
    if (mb_ch < 128)    mb_ch = 128;

    char* pool = ws + off;
    dim3 blk(256);
    dim3 blkg(1024);

    // 0) conversions
    {
        f32_to_split_kernel<<<(N_CAND*D_IN + 255)/256, blk, 0, stream>>>(cand_x, in_h, in_l, N_CAND*D_IN);
        f32_to_split_kernel<<<(B_ROWS*D_IN + 255)/256, blk, 0, stream>>>(x, x_in_h, x_in_l, B_ROWS*D_IN);
        TrDs tr;
        tr.d[0]  = { W_lin, WlinTh, WlinTl, D_IN,   D_MAIN };
        tr.d[1]  = { e0W1,  e0W1Th, e0W1Tl, D_MAIN, D_BLOCK };
        tr.d[2]  = { e0W2,  e0W2Th, e0W2Tl, D_BLOCK,D_MAIN };
        tr.d[3]  = { e1W1,  e1W1Th, e1W1Tl, D_MAIN, D_BLOCK };
        tr.d[4]  = { e1W2,  e1W2Th, e1W2Tl, D_BLOCK,D_MAIN };
        tr.d[5]  = { K_W,   KWTh,   KWTl,   D_MAIN, D_MAIN };
        tr.d[6]  = { T_W1,  TW1Th,  TW1Tl,  D_MAIN, D_BLOCK };
        tr.d[7]  = { p0W1,  p0W1Th, p0W1Tl, D_MAIN, D_BLOCK };
        tr.d[8]  = { p0W2,  p0W2Th, p0W2Tl, D_BLOCK,D_MAIN };
        tr.d[9]  = { p1W1,  p1W1Th, p1W1Tl, D_MAIN, D_BLOCK };
        tr.d[10] = { p1W2,  p1W2Th, p1W2Tl, D_BLOCK,D_MAIN };
        transpose_all_kernel<<<dim3(512, 11), blk, 0, stream>>>(tr);
    }

    EncW w = { WlinTh, WlinTl, e0W1Th, e0W1Tl, e0W2Th, e0W2Tl,
               e1W1Th, e1W1Tl, e1W2Th, e1W2Tl, KWTh, KWTl,
               b_lin, e0b1, e0b2, e1g, e1b, e1b1, e1b2, mixg, mixb, K_b };

    // 1) combined encode (candidates + x)
    for (int r0 = 0; r0 < NTOT; r0 += rc_enc) {
        const int R = (NTOT - r0 < rc_enc) ? (NTOT - r0) : rc_enc;
        char* p = pool;
        float* Hc = (float*)p;        p += (size_t)rc_enc * D_MAIN * 4;
        u16* Hh  = (u16*)p;           p += (size_t)rc_enc * D_MAIN * 2;
        u16* Hl  = (u16*)p;           p += (size_t)rc_enc * D_MAIN * 2;
        u16* Th  = (u16*)p;           p += (size_t)rc_enc * D_BLOCK * 2;
        u16* Tl  = (u16*)p;           p += (size_t)rc_enc * D_BLOCK * 2;
        u16* TNh = (u16*)p;           p += (size_t)rc_enc * D_MAIN * 2;
        u16* TNl = (u16*)p;
        encode_rows_split(in_h + (size_t)r0 * D_IN, in_l + (size_t)r0 * D_IN,
                          R, w, Hc, Hh, Hl, Th, Tl, TNh, TNl,
                          allk_h + (size_t)r0 * D_MAIN,
                          allk_l + (size_t)r0 * D_MAIN, stream);
        const int lo = (r0 > N_CAND) ? r0 : N_CAND;
        const int hi = (r0 + R < NTOT) ? r0 + R : NTOT;
        if (lo < hi) {
            const int n = (hi - lo) * D_MAIN;
            copy_rows_kernel<<<(n + 255)/256, blk, 0, stream>>>(
                Hc + (size_t)(lo - r0) * D_MAIN, h_x + (size_t)(lo - N_CAND) * D_MAIN, n);
        }
    }

    // 2) candidate norms
    cn2_kernel<<<N_CAND, 64, 0, stream>>>(allk_h, allk_l, ck2);

    // 3+4) distance keys (bf16-hi only) + top-96 select (2-pass + cand list)
    for (int m0 = 0; m0 < B_ROWS; m0 += mb_ch) {
        const int R = (B_ROWS - m0 < mb_ch) ? (B_ROWS - m0) : mb_ch;
        u16* s_keys = (u16*)pool;
        unsigned* candbuf = (unsigned*)(pool + (size_t)mb_ch * N_CAND * 2);
        dim3 grid((unsigned)((R + 127) / 128), (unsigned)((N_CAND + 127) / 128));
        gemm_split_nt<false,false,false,true, false,false,false, false,false,true><<<grid, blkg, 0, stream>>>(
            k_x_h + (size_t)m0 * D_MAIN, nullptr,
            allk_h, nullptr, ck2, nullptr, nullptr, s_keys, nullptr,
            R, N_CAND, D_MAIN);
        topk96_u16_kernel<<<R, 1024, 0, stream>>>(
            s_keys, idx + m0 * CTX, tiebuf + (size_t)m0 * MAXTIE,
            tiecnt + m0, lesscnt + m0, candbuf);
    }

    // 5) fused exact tie-break + sval + softmax
    select_kernel<<<B_ROWS, 256, 0, stream>>>(k_x_h, k_x_l, allk_h, allk_l, ck2,
                                              tiebuf, tiecnt, lesscnt, idx, probs);

    // 6) T-MLP via linearity of W1 and W2:
    //    Q = allk @ T_W1 (all NTOT rows, fp32). tmix collapses
    //    relu(P_b + b1 - Q_c) with probs, folds the label mix AND the
    //    u @ T_W2 product (fp32 W2, coalesced row reads) into h_x.
    float* Qbuf = (float*)tiebuf;   // tiebuf + pool; needs ~99.7 MiB total
    gemm_split_nt<false,false,false,false, true,false,false, true,true,false><<<g128(NTOT, D_BLOCK), blkg, 0, stream>>>(
        allk_h, allk_l, TW1Th, TW1Tl, nullptr, nullptr, Qbuf, nullptr, nullptr,
        NTOT, D_BLOCK, D_MAIN);
    tmix_kernel<<<B_ROWS, 256, 0, stream>>>(Qbuf, T_b1, T_W2, probs, idx,
                                            cand_y, label_emb, h_x);

    // 7) post blocks (split MFMA, fp32-quality)
    ln_kernel<false,true><<<B_ROWS, 256, 0, stream>>>(h_x, p0g, p0b, nullptr, tnb_h, tnb_l);
    gemm_split_nt<true,true,false,false, false,true,false, true,true,false><<<g128(B_ROWS, D_BLOCK), blkg, 0, stream>>>(
        tnb_h, tnb_l, p0W1Th, p0W1Tl, p0b1, nullptr, nullptr, tb_h, tb_l, B_ROWS, D_BLOCK, D_MAIN);
    gemm_split_nt<false,true,true,false, true,false,false, true,true,false><<<g128(B_ROWS, D_MAIN), blkg, 0, stream>>>(
        tb_h, tb_l, p0W2Th, p0W2Tl, p0b2, h_x, h_x, nullptr, nullptr, B_ROWS, D_MAIN, D_BLOCK);
    ln_kernel<false,true><<<B_ROWS, 256, 0, stream>>>(h_x, p1g, p1b, nullptr, tnb_h, tnb_l);
    gemm_split_nt<true,true,false,false, false,true,false, true,true,false><<<g128(B_ROWS, D_BLOCK), blkg, 0, stream>>>(
        tnb_h, tnb_l, p1W1Th, p1W1Tl, p1b1, nullptr, nullptr, tb_h, tb_l, B_ROWS, D_BLOCK, D_MAIN);
    gemm_split_nt<false,true,true,false, true,false,false, true,true,false><<<g128(B_ROWS, D_MAIN), blkg, 0, stream>>>(
        tb_h, tb_l, p1W2Th, p1W2Tl, p1b2, h_x, h_x, nullptr, nullptr, B_ROWS, D_MAIN, D_BLOCK);

    // 8) head (fp32)
    ln_kernel<true,false><<<B_ROWS, 256, 0, stream>>>(h_x, headg, headb, tn_x, nullptr, nullptr);
    gemm_head<<<dim3(1, (B_ROWS + 63) / 64), blk, 0, stream>>>(
        tn_x, head_W, head_bias, (float*)d_out, B_ROWS, N_OUT, D_MAIN);
}